// Round 13
// baseline (5760.728 us; speedup 1.0000x reference)
//
#include <hip/hip_runtime.h>
#include <stdint.h>

#define SEQ 512
#define BAT 64
#define INF 256     // input features
#define HID 1024
#define SB  (SEQ*BAT)   // 32768 rows
#define G_WGS 64            // WGs per pipeline group
#define NWG (3*G_WGS)       // 192 persistent WGs

typedef __attribute__((ext_vector_type(8))) short short8;
typedef __attribute__((ext_vector_type(4))) float f32x4;

union Frag8 { uint32_t u[4]; short8 s; };

// ---------- numeric helpers: fp32 <-> (bf16 hi, bf16 lo) ----------
__device__ __forceinline__ uint32_t bf16hi_rne(uint32_t u){
  return (u + 0x7FFFu + ((u >> 16) & 1u)) & 0xFFFF0000u;
}
__device__ __forceinline__ uint32_t pack_split(float v){
  uint32_t hi = bf16hi_rne(__float_as_uint(v));
  float r = v - __uint_as_float(hi);
  uint32_t lo = bf16hi_rne(__float_as_uint(r)) >> 16;
  return hi | lo;                              // (hi16<<16) | lo16
}
__device__ __forceinline__ void unpack_pair(uint32_t u0, uint32_t u1,
                                            uint32_t& h, uint32_t& l){
  h = __builtin_amdgcn_perm(u1, u0, 0x07060302u);  // {u0.b2,u0.b3,u1.b2,u1.b3}
  l = __builtin_amdgcn_perm(u1, u0, 0x05040100u);  // {u0.b0,u0.b1,u1.b0,u1.b1}
}
__device__ __forceinline__ void gl16(const void* g, void* l){
  __builtin_amdgcn_global_load_lds(
      (const __attribute__((address_space(1))) void*)g,
      (__attribute__((address_space(3))) void*)l, 16, 0, 0);
}

// ---------- agent-scope atomics (flags + cross-WG visible writes) ----------
__device__ __forceinline__ void astore32(uint32_t* p, uint32_t v){
  __hip_atomic_store(p, v, __ATOMIC_RELAXED, __HIP_MEMORY_SCOPE_AGENT);
}
// wave-cooperative poll: lanes 0..31 each watch one producer flag
__device__ __forceinline__ void waitflags32(uint32_t* base, uint32_t tgt){
  const int lane = threadIdx.x & 63;
  unsigned spins = 0;
  for (;;){
    uint32_t v = (lane < 32)
        ? __hip_atomic_load(base + lane, __ATOMIC_RELAXED, __HIP_MEMORY_SCOPE_AGENT)
        : 0xFFFFFFFFu;
    if (__all(v >= tgt)) break;
    __builtin_amdgcn_s_sleep(1);
    if (++spins > (1u << 20)) break;   // failsafe: fail fast, never wedge
  }
}

// ---------- prep kernels ----------
__global__ __launch_bounds__(256) void wcomb_kernel(const float* __restrict__ A,
                                                    const float* __restrict__ B,
                                                    float* __restrict__ C){
  __shared__ float As[16][64];
  __shared__ float Bs[64][256];
  const int tid = threadIdx.x;
  const int g0 = blockIdx.x * 16;
  float acc[16];
#pragma unroll
  for (int g = 0; g < 16; ++g) acc[g] = 0.f;
  for (int h0 = 0; h0 < HID; h0 += 64){
    __syncthreads();
#pragma unroll
    for (int j = 0; j < 4; ++j){
      int c = j*256 + tid;
      As[c >> 6][c & 63] = A[(size_t)(g0 + (c >> 6))*HID + h0 + (c & 63)];
    }
#pragma unroll
    for (int j = 0; j < 64; ++j) Bs[j][tid] = B[(size_t)(h0 + j)*INF + tid];
    __syncthreads();
#pragma unroll
    for (int hh = 0; hh < 64; hh += 4){
      float b0 = Bs[hh][tid], b1 = Bs[hh+1][tid], b2 = Bs[hh+2][tid], b3 = Bs[hh+3][tid];
#pragma unroll
      for (int g = 0; g < 16; ++g){
        const float4 a = *(const float4*)&As[g][hh];
        acc[g] += a.x*b0 + a.y*b1 + a.z*b2 + a.w*b3;
      }
    }
  }
#pragma unroll
  for (int g = 0; g < 16; ++g) C[(size_t)(g0 + g)*INF + tid] = acc[g];
}

__global__ __launch_bounds__(256) void bcomb_kernel(const float* __restrict__ Wih0,
                                                    const float* __restrict__ bin,
                                                    const float* __restrict__ bih0,
                                                    float* __restrict__ bcomb){
  __shared__ float r[4];
  const int g = blockIdx.x, tid = threadIdx.x;
  float s = 0.f;
  for (int h = tid; h < HID; h += 256) s += Wih0[(size_t)g*HID + h] * bin[h];
  for (int o = 32; o > 0; o >>= 1) s += __shfl_down(s, o, 64);
  if ((tid & 63) == 0) r[tid >> 6] = s;
  __syncthreads();
  if (tid == 0) bcomb[g] = bih0[g] + r[0] + r[1] + r[2] + r[3];
}

__global__ void split_w(const float* __restrict__ in, uint16_t* __restrict__ hi,
                        uint16_t* __restrict__ lo, int n){
  int i = blockIdx.x*256 + threadIdx.x;
  if (i < n){
    float v = in[i];
    uint32_t h = bf16hi_rne(__float_as_uint(v));
    float r = v - __uint_as_float(h);
    hi[i] = (uint16_t)(h >> 16);
    lo[i] = (uint16_t)(bf16hi_rne(__float_as_uint(r)) >> 16);
  }
}

__global__ void pack_x(const float* __restrict__ in, uint32_t* __restrict__ out, int n){
  int i = blockIdx.x*256 + threadIdx.x;
  if (i < n) out[i] = pack_split(in[i]);
}

// ---------- batched split GEMM (pre0 / out): C = unpack(A) @ (Whi+Wlo)^T + bias ----------
__global__ __launch_bounds__(256) void gemm_split(
    const uint32_t* __restrict__ A, const uint16_t* __restrict__ Whi,
    const uint16_t* __restrict__ Wlo, const float* __restrict__ bias,
    float* __restrict__ C, int N, int K)
{
  __shared__ uint32_t Al[128*32];
  __shared__ uint16_t Wh[128*32];
  __shared__ uint16_t Wl[128*32];
  const int tid  = threadIdx.x;
  const int lane = tid & 63;
  const int w    = tid >> 6;
  const int wm   = w >> 1, wn = w & 1;
  const int lr   = lane & 15, kg = lane >> 4;
  const int bm   = blockIdx.x, bn = blockIdx.y;

  const uint32_t* Ag  = A   + (size_t)bm*128*K;
  const uint16_t* Whg = Whi + (size_t)bn*128*K;
  const uint16_t* Wlg = Wlo + (size_t)bn*128*K;

  f32x4 acc[4][4];
#pragma unroll
  for (int i = 0; i < 4; ++i)
#pragma unroll
    for (int j = 0; j < 4; ++j) acc[i][j] = (f32x4){0.f,0.f,0.f,0.f};

  for (int ks = 0; ks < K; ks += 32){
    __syncthreads();
#pragma unroll
    for (int j = 0; j < 4; ++j){
      int c = j*256 + tid;
      int row = c >> 3, kc = c & 7;
      int kcs = kc ^ ((row & 3) << 1);
      gl16(Ag + (size_t)row*K + ks + kcs*4, (char*)Al + c*16);
    }
#pragma unroll
    for (int j = 0; j < 2; ++j){
      int c = j*256 + tid;
      int row = c >> 2, kc = c & 3;
      int kcs = kc ^ (row & 3);
      gl16(Whg + (size_t)row*K + ks + kcs*8, (char*)Wh + c*16);
      gl16(Wlg + (size_t)row*K + ks + kcs*8, (char*)Wl + c*16);
    }
    __syncthreads();

    short8 ah[4], al[4];
#pragma unroll
    for (int mt = 0; mt < 4; ++mt){
      int row = wm*64 + mt*16 + lr;
      int c2  = kg ^ (row & 3);
      const uint32_t* p = &Al[row*32 + c2*8];
      uint4 a0 = *(const uint4*)p;
      uint4 a1 = *(const uint4*)(p + 4);
      Frag8 fh, fl;
      unpack_pair(a0.x, a0.y, fh.u[0], fl.u[0]);
      unpack_pair(a0.z, a0.w, fh.u[1], fl.u[1]);
      unpack_pair(a1.x, a1.y, fh.u[2], fl.u[2]);
      unpack_pair(a1.z, a1.w, fh.u[3], fl.u[3]);
      ah[mt] = fh.s; al[mt] = fl.s;
    }
#pragma unroll
    for (int nt = 0; nt < 4; ++nt){
      int row = wn*64 + nt*16 + lr;
      int kc  = kg ^ (row & 3);
      short8 whf = *(const short8*)&Wh[row*32 + kc*8];
      short8 wlf = *(const short8*)&Wl[row*32 + kc*8];
#pragma unroll
      for (int mt = 0; mt < 4; ++mt){
        acc[mt][nt] = __builtin_amdgcn_mfma_f32_16x16x32_bf16(ah[mt], whf, acc[mt][nt], 0,0,0);
        acc[mt][nt] = __builtin_amdgcn_mfma_f32_16x16x32_bf16(al[mt], whf, acc[mt][nt], 0,0,0);
        acc[mt][nt] = __builtin_amdgcn_mfma_f32_16x16x32_bf16(ah[mt], wlf, acc[mt][nt], 0,0,0);
      }
    }
  }
#pragma unroll
  for (int nt = 0; nt < 4; ++nt){
    int col = bn*128 + wn*64 + nt*16 + lr;
    float bv = bias[col];
#pragma unroll
    for (int mt = 0; mt < 4; ++mt){
#pragma unroll
      for (int r = 0; r < 4; ++r){
        int rowg = bm*128 + wm*64 + mt*16 + kg*4 + r;
        C[(size_t)rowg*N + col] = acc[mt][nt][r] + bv;
      }
    }
  }
}

// ---------- persistent wavefront scan ----------
// 192 WGs x 256 thr. group = wg/64: 0 = L0 rec (t=r), 1 = Wih1*h0 (t=r-1),
// 2 = L1 rec (t=r-2). sub=wg%64: rh=sub>>5 (32-row half), ci=sub&31 (32-col).
// W slice in LDS fragment-linear (128 KB). A: 16 chunks x 8 KB, 4 LDS slots,
// 3-deep prefetch, counted vmcnt(4/2/0), ONE s_barrier per chunk.
// Flags: PER-PRODUCER words (no atomic RMW): flag[(group*2+rh)*64 + ci] = t+1
// via plain relaxed store after drain; consumers poll their 32 same-rh
// producer flags with a vectorized wave-ballot loop.
__global__ __launch_bounds__(256, 1) void rnn_persist(
    const float* __restrict__ pre0, uint32_t* __restrict__ h0seq,
    uint32_t* __restrict__ pre1, uint32_t* __restrict__ h1seq,
    const uint16_t* __restrict__ Whh0h, const uint16_t* __restrict__ Whh0l,
    const uint16_t* __restrict__ Wih1h, const uint16_t* __restrict__ Wih1l,
    const uint16_t* __restrict__ Whh1h, const uint16_t* __restrict__ Whh1l,
    const float* __restrict__ bhh0, const float* __restrict__ bih1,
    const float* __restrict__ bhh1,
    uint32_t* h0s, uint32_t* h1s,
    uint32_t* ctr, int T, int first)
{
  __shared__ short WhF[32768];        // 64 KB, fragment-linear
  __shared__ short WlF[32768];        // 64 KB
  __shared__ uint32_t Abuf[4][2048];  // 4 x 8 KB A chunks (total = exactly 160 KiB)
  const int tid  = threadIdx.x;
  const int lane = tid & 63;
  const int w    = tid >> 6;                 // 0..3
  const int mt   = w >> 1, ntw = w & 1;
  const int lr   = lane & 15, kg = lane >> 4;
  const int wg   = blockIdx.x;
  const int group = wg / G_WGS;              // 0,1,2
  const int sub  = wg % G_WGS;
  const int rh   = sub >> 5;                 // 0..1 (rows 32*rh)
  const int ci   = sub & 31;                 // 0..31 (cols 32*ci)
  const int col0 = ci * 32;

  // per-producer flag blocks: (group*2+rh)*64 u32 (32 used, 256B apart)
  uint32_t* fmy = ctr + (group*2 + rh)*64;         // my block; I write fmy[ci]
  uint32_t* f0  = ctr + (0*2 + rh)*64;             // G0 flags, same rh
  uint32_t* f1  = ctr + (1*2 + rh)*64;             // G1 flags, same rh
  uint32_t* f2  = ctr + (2*2 + rh)*64;             // G2 flags, same rh

  const uint16_t* Whg = (group == 0) ? Whh0h : (group == 1) ? Wih1h : Whh1h;
  const uint16_t* Wlg = (group == 0) ? Whh0l : (group == 1) ? Wih1l : Whh1l;

  // ---- stage W slice into LDS once, fragment-linear ----
#pragma unroll
  for (int it = 0; it < 16; ++it){
    int lin = it*256 + tid;          // 0..4095
    int c = lin >> 7, j = lin & 127;
    int dst = (((c >> 4)*32 + (j >> 2))*64 + (j & 3)*16 + (c & 15))*8;
    *(uint4*)&WhF[dst] = *(const uint4*)&Whg[(size_t)(col0 + c)*HID + j*8];
    *(uint4*)&WlF[dst] = *(const uint4*)&Wlg[(size_t)(col0 + c)*HID + j*8];
  }
  __syncthreads();

  const int fragbase = ntw*16384 + lane*8;       // shorts; + ks*512
  const int arow = mt*16 + lr;                   // local A row this lane reads
  const int p3r  = ((arow & 3) << 1) | ((arow >> 2) & 1);

  const int col = col0 + ntw*16 + lr;
  const float bvg = (group == 0) ? bhh0[col]
                   : (group == 1) ? (bih1[col] + bhh1[col]) : 0.f;

  const int R = T + 2;
  for (int r = 0; r < R; ++r){
    const int t = r - group;
    const bool valid = (t >= 0 && t < T);

    // ---- dependency waits: vectorized per-producer flag polls ----
    if (valid){
      if (group == 0){
        if (w == 0 && t > 0) waitflags32(f0, (uint32_t)t);
      } else if (group == 1){
        if (w == 0) waitflags32(f0, (uint32_t)(t+1));
      } else {
        if (w == 0) waitflags32(f1, (uint32_t)(t+1));
        else if (w == 1 && t > 0) waitflags32(f2, (uint32_t)t);
      }
    }
    __syncthreads();
    asm volatile("" ::: "memory");

    if (valid){
      const uint32_t* Ap;
      if (group == 0)
        Ap = (t == 0) ? (first ? (const uint32_t*)0 : h0s)
                      : h0seq + (size_t)(t-1)*(BAT*HID);
      else if (group == 1)
        Ap = h0seq + (size_t)t*(BAT*HID);
      else
        Ap = (t == 0) ? (first ? (const uint32_t*)0 : h1s)
                      : h1seq + (size_t)(t-1)*(BAT*HID);

      // hoisted epilogue-input loads (overlap with DMA pipeline)
      const int rowb = rh*32 + mt*16 + kg*4;
      const size_t idx0 = (size_t)t*(BAT*HID) + (size_t)rowb*HID + col;
      float pv[4] = {0.f,0.f,0.f,0.f};
      if (group == 0){
#pragma unroll
        for (int q = 0; q < 4; ++q) pv[q] = pre0[idx0 + (size_t)q*HID];
      } else if (group == 2){
#pragma unroll
        for (int q = 0; q < 4; ++q) pv[q] = __uint_as_float(pre1[idx0 + (size_t)q*HID]);
      }

      f32x4 acc[4];
#pragma unroll
      for (int i = 0; i < 4; ++i) acc[i] = (f32x4){0.f,0.f,0.f,0.f};

      if (Ap){
        // chunk k (0..15): rows [rh*32,+32) x K-elems [k*64,+64) (8 KB).
        // slot s=0..511: row=s>>4, pos=s&15 (16B units); src pos ^= p3(row).
        auto STAGE = [&](int k){
          const int sl = k & 3;
#pragma unroll
          for (int j = 0; j < 2; ++j){
            const int slot  = w*128 + j*64 + lane;
            const int row_l = slot >> 4;
            const int pos   = slot & 15;
            const int p3 = ((row_l & 3) << 1) | ((row_l >> 2) & 1);
            const uint32_t* src = Ap + (size_t)(rh*32 + row_l)*HID + k*64 + (pos ^ p3)*4;
            gl16(src, (char*)&Abuf[sl][0] + (w*128 + j*64)*16 + lane*16);
          }
        };

        STAGE(0); STAGE(1); STAGE(2);
#pragma unroll
        for (int k = 0; k < 16; ++k){
          if (k < 14)      asm volatile("s_waitcnt vmcnt(4)" ::: "memory");
          else if (k == 14) asm volatile("s_waitcnt vmcnt(2)" ::: "memory");
          else              asm volatile("s_waitcnt vmcnt(0)" ::: "memory");
          __builtin_amdgcn_s_barrier();
          __builtin_amdgcn_sched_barrier(0);
          if (k < 13) STAGE(k+3);
          const uint32_t* Ab = &Abuf[k & 3][arow*64];
#pragma unroll
          for (int s2 = 0; s2 < 2; ++s2){
            const int ks = k*2 + s2;
            const int sA = ((s2 << 3) + (kg << 1)) ^ p3r;
            uint4 a0 = *(const uint4*)&Ab[sA*4];
            uint4 a1 = *(const uint4*)&Ab[(sA^1)*4];
            Frag8 fh, fl;
            unpack_pair(a0.x, a0.y, fh.u[0], fl.u[0]);
            unpack_pair(a0.z, a0.w, fh.u[1], fl.u[1]);
            unpack_pair(a1.x, a1.y, fh.u[2], fl.u[2]);
            unpack_pair(a1.z, a1.w, fh.u[3], fl.u[3]);
            short8 whf = *(const short8*)&WhF[fragbase + ks*512];
            short8 wlf = *(const short8*)&WlF[fragbase + ks*512];
            acc[ks & 3] = __builtin_amdgcn_mfma_f32_16x16x32_bf16(fh.s, whf, acc[ks & 3], 0,0,0);
            acc[ks & 3] = __builtin_amdgcn_mfma_f32_16x16x32_bf16(fl.s, whf, acc[ks & 3], 0,0,0);
            acc[ks & 3] = __builtin_amdgcn_mfma_f32_16x16x32_bf16(fh.s, wlf, acc[ks & 3], 0,0,0);
          }
        }
      }
      f32x4 s = (acc[0] + acc[1]) + (acc[2] + acc[3]);

      // ---- epilogue ----
      if (group == 0){
#pragma unroll
        for (int q = 0; q < 4; ++q){
          const size_t idx = idx0 + (size_t)q*HID;
          float v = tanhf(s[q] + pv[q] + bvg);
          uint32_t pk = pack_split(v);
          astore32(h0seq + idx, pk);
          if (t == T-1) astore32(h0s + (size_t)(rowb + q)*HID + col, pk);
        }
      } else if (group == 1){
#pragma unroll
        for (int q = 0; q < 4; ++q){
          const size_t idx = idx0 + (size_t)q*HID;
          astore32(pre1 + idx, __float_as_uint(s[q] + bvg));
        }
      } else {
#pragma unroll
        for (int q = 0; q < 4; ++q){
          const size_t idx = idx0 + (size_t)q*HID;
          float v = tanhf(s[q] + pv[q]);
          uint32_t pk = pack_split(v);
          astore32(h1seq + idx, pk);
          if (t == T-1) astore32(h1s + (size_t)(rowb + q)*HID + col, pk);
        }
      }
    }

    // drain stores to the coherence point, then per-producer flag store
    asm volatile("s_waitcnt vmcnt(0) lgkmcnt(0)" ::: "memory");
    __syncthreads();
    if (tid == 0 && valid)
      astore32(fmy + ci, (uint32_t)(t + 1));
  }
}

// ---------- hidden output from carried states ----------
__global__ void extract_hidden(const uint32_t* __restrict__ h0s,
                               const uint32_t* __restrict__ h1s,
                               float* __restrict__ out){
  int i = blockIdx.x*256 + threadIdx.x;   // 0..131071
  uint32_t p = (i >> 16) ? h1s[i & 65535] : h0s[i & 65535];
  out[(size_t)SB*INF + i] = __uint_as_float(p & 0xFFFF0000u) + __uint_as_float(p << 16);
}

// ---------- host ----------
extern "C" void kernel_launch(void* const* d_in, const int* in_sizes, int n_in,
                              void* d_out, int out_size, void* d_ws, size_t ws_size,
                              hipStream_t stream)
{
  const float* x    = (const float*)d_in[0];
  const float* W_in = (const float*)d_in[1];
  const float* b_in = (const float*)d_in[2];
  const float* W_ih = (const float*)d_in[3];   // [2][H][H]
  const float* W_hh = (const float*)d_in[4];   // [2][H][H]
  const float* b_ih = (const float*)d_in[5];   // [2][H]
  const float* b_hh = (const float*)d_in[6];   // [2][H]
  const float* W_out= (const float*)d_in[7];   // [I][H]
  const float* b_out= (const float*)d_in[8];
  float* out = (float*)d_out;
  (void)in_sizes; (void)n_in; (void)out_size;

  // ---- choose chunk length T to fit ws_size ----
  const size_t fixedB = 16257024 + 16384;
  const size_t perT   = 1114112;
  int T = 512;
  while (T > 2 && fixedB + (size_t)T*perT + 65536 > ws_size) T >>= 1;
  const int nchunk = SEQ / T;

  char* ws = (char*)d_ws;
  size_t off = 0;
  auto alloc = [&](size_t bytes)->void*{
    void* p = ws + off; off += (bytes + 255) & ~(size_t)255; return p;
  };
  float*    pre0s  = (float*)   alloc((size_t)T*BAT*HID*4);
  uint32_t* h0seq  = (uint32_t*)alloc((size_t)T*BAT*HID*4);
  uint32_t* pre1s  = (uint32_t*)alloc((size_t)T*BAT*HID*4);
  uint32_t* h1seq  = (uint32_t*)alloc((size_t)T*BAT*HID*4);
  uint32_t* xp     = (uint32_t*)alloc((size_t)T*BAT*INF*4);
  float*    WcombF = (float*)   alloc((size_t)HID*INF*4);
  uint16_t* Wc_hi  = (uint16_t*)alloc((size_t)HID*INF*2);
  uint16_t* Wc_lo  = (uint16_t*)alloc((size_t)HID*INF*2);
  uint16_t* Wih1_hi= (uint16_t*)alloc((size_t)HID*HID*2);
  uint16_t* Wih1_lo= (uint16_t*)alloc((size_t)HID*HID*2);
  uint16_t* Whh0_hi= (uint16_t*)alloc((size_t)HID*HID*2);
  uint16_t* Whh0_lo= (uint16_t*)alloc((size_t)HID*HID*2);
  uint16_t* Whh1_hi= (uint16_t*)alloc((size_t)HID*HID*2);
  uint16_t* Whh1_lo= (uint16_t*)alloc((size_t)HID*HID*2);
  uint16_t* Wout_hi= (uint16_t*)alloc((size_t)INF*HID*2);
  uint16_t* Wout_lo= (uint16_t*)alloc((size_t)INF*HID*2);
  float*    bcomb  = (float*)   alloc((size_t)HID*4);
  uint32_t* h0s    = (uint32_t*)alloc((size_t)BAT*HID*4);
  uint32_t* h1s    = (uint32_t*)alloc((size_t)BAT*HID*4);
  uint32_t* ctr    = (uint32_t*)alloc(8192);

  // ---- prep ----
  wcomb_kernel<<<HID/16, 256, 0, stream>>>(W_ih, W_in, WcombF);
  bcomb_kernel<<<HID, 256, 0, stream>>>(W_ih, b_in, b_ih, bcomb);
  split_w<<<(HID*INF+255)/256, 256, 0, stream>>>(WcombF, Wc_hi, Wc_lo, HID*INF);
  split_w<<<(HID*HID+255)/256, 256, 0, stream>>>(W_ih + (size_t)HID*HID, Wih1_hi, Wih1_lo, HID*HID);
  split_w<<<(HID*HID+255)/256, 256, 0, stream>>>(W_hh, Whh0_hi, Whh0_lo, HID*HID);
  split_w<<<(HID*HID+255)/256, 256, 0, stream>>>(W_hh + (size_t)HID*HID, Whh1_hi, Whh1_lo, HID*HID);
  split_w<<<(INF*HID+255)/256, 256, 0, stream>>>(W_out, Wout_hi, Wout_lo, INF*HID);

  // ---- chunked pipeline ----
  for (int c = 0; c < nchunk; ++c){
    const float* xc = x + (size_t)c*T*BAT*INF;
    pack_x<<<T*BAT*INF/256, 256, 0, stream>>>(xc, xp, T*BAT*INF);
    // pre0 chunk = xp @ Wcomb^T + bcomb
    gemm_split<<<dim3(T*64/128, HID/128), 256, 0, stream>>>(xp, Wc_hi, Wc_lo, bcomb, pre0s, HID, INF);
    // wavefront scan over the chunk (both layers + pre1 fused)
    hipMemsetAsync(ctr, 0, 8192, stream);
    rnn_persist<<<NWG, 256, 0, stream>>>(
        pre0s, h0seq, pre1s, h1seq,
        Whh0_hi, Whh0_lo, Wih1_hi, Wih1_lo, Whh1_hi, Whh1_lo,
        b_hh, b_ih + HID, b_hh + HID, h0s, h1s, ctr, T, (c == 0) ? 1 : 0);
    // out chunk = h1chunk @ Wout^T + b_out
    gemm_split<<<dim3(T*64/128, INF/128), 256, 0, stream>>>(h1seq, Wout_hi, Wout_lo,
                                                            b_out, out + (size_t)c*T*BAT*INF, INF, HID);
  }
  extract_hidden<<<(2*BAT*HID)/256, 256, 0, stream>>>(h0s, h1s, out);
}

// Round 14
// 4813.939 us; speedup vs baseline: 1.1967x; 1.1967x over previous
//
#include <hip/hip_runtime.h>
#include <stdint.h>

#define SEQ 512
#define BAT 64
#define INF 256     // input features
#define HID 1024
#define SB  (SEQ*BAT)   // 32768 rows
#define G_WGS 64            // WGs per pipeline group
#define NWG (3*G_WGS)       // 192 persistent WGs

typedef __attribute__((ext_vector_type(8))) short short8;
typedef __attribute__((ext_vector_type(4))) float f32x4;

union Frag8 { uint32_t u[4]; short8 s; };

// ---------- numeric helpers: fp32 <-> (bf16 hi, bf16 lo) ----------
__device__ __forceinline__ uint32_t bf16hi_rne(uint32_t u){
  return (u + 0x7FFFu + ((u >> 16) & 1u)) & 0xFFFF0000u;
}
__device__ __forceinline__ uint32_t pack_split(float v){
  uint32_t hi = bf16hi_rne(__float_as_uint(v));
  float r = v - __uint_as_float(hi);
  uint32_t lo = bf16hi_rne(__float_as_uint(r)) >> 16;
  return hi | lo;                              // (hi16<<16) | lo16
}
__device__ __forceinline__ void unpack_pair(uint32_t u0, uint32_t u1,
                                            uint32_t& h, uint32_t& l){
  h = __builtin_amdgcn_perm(u1, u0, 0x07060302u);  // {u0.b2,u0.b3,u1.b2,u1.b3}
  l = __builtin_amdgcn_perm(u1, u0, 0x05040100u);  // {u0.b0,u0.b1,u1.b0,u1.b1}
}
__device__ __forceinline__ void gl16(const void* g, void* l){
  __builtin_amdgcn_global_load_lds(
      (const __attribute__((address_space(1))) void*)g,
      (__attribute__((address_space(3))) void*)l, 16, 0, 0);
}

// ---------- agent-scope atomics (flags + cross-WG visible writes) ----------
__device__ __forceinline__ void astore32(uint32_t* p, uint32_t v){
  __hip_atomic_store(p, v, __ATOMIC_RELAXED, __HIP_MEMORY_SCOPE_AGENT);
}
// wave-cooperative poll: lanes 0..31 each watch one producer flag
__device__ __forceinline__ void waitflags32(uint32_t* base, uint32_t tgt){
  const int lane = threadIdx.x & 63;
  unsigned spins = 0;
  for (;;){
    uint32_t v = (lane < 32)
        ? __hip_atomic_load(base + lane, __ATOMIC_RELAXED, __HIP_MEMORY_SCOPE_AGENT)
        : 0xFFFFFFFFu;
    if (__all(v >= tgt)) break;
    __builtin_amdgcn_s_sleep(1);
    if (++spins > (1u << 20)) break;   // failsafe: fail fast, never wedge
  }
}

// ---------- prep kernels ----------
__global__ __launch_bounds__(256) void wcomb_kernel(const float* __restrict__ A,
                                                    const float* __restrict__ B,
                                                    float* __restrict__ C){
  __shared__ float As[16][64];
  __shared__ float Bs[64][256];
  const int tid = threadIdx.x;
  const int g0 = blockIdx.x * 16;
  float acc[16];
#pragma unroll
  for (int g = 0; g < 16; ++g) acc[g] = 0.f;
  for (int h0 = 0; h0 < HID; h0 += 64){
    __syncthreads();
#pragma unroll
    for (int j = 0; j < 4; ++j){
      int c = j*256 + tid;
      As[c >> 6][c & 63] = A[(size_t)(g0 + (c >> 6))*HID + h0 + (c & 63)];
    }
#pragma unroll
    for (int j = 0; j < 64; ++j) Bs[j][tid] = B[(size_t)(h0 + j)*INF + tid];
    __syncthreads();
#pragma unroll
    for (int hh = 0; hh < 64; hh += 4){
      float b0 = Bs[hh][tid], b1 = Bs[hh+1][tid], b2 = Bs[hh+2][tid], b3 = Bs[hh+3][tid];
#pragma unroll
      for (int g = 0; g < 16; ++g){
        const float4 a = *(const float4*)&As[g][hh];
        acc[g] += a.x*b0 + a.y*b1 + a.z*b2 + a.w*b3;
      }
    }
  }
#pragma unroll
  for (int g = 0; g < 16; ++g) C[(size_t)(g0 + g)*INF + tid] = acc[g];
}

__global__ __launch_bounds__(256) void bcomb_kernel(const float* __restrict__ Wih0,
                                                    const float* __restrict__ bin,
                                                    const float* __restrict__ bih0,
                                                    float* __restrict__ bcomb){
  __shared__ float r[4];
  const int g = blockIdx.x, tid = threadIdx.x;
  float s = 0.f;
  for (int h = tid; h < HID; h += 256) s += Wih0[(size_t)g*HID + h] * bin[h];
  for (int o = 32; o > 0; o >>= 1) s += __shfl_down(s, o, 64);
  if ((tid & 63) == 0) r[tid >> 6] = s;
  __syncthreads();
  if (tid == 0) bcomb[g] = bih0[g] + r[0] + r[1] + r[2] + r[3];
}

__global__ void split_w(const float* __restrict__ in, uint16_t* __restrict__ hi,
                        uint16_t* __restrict__ lo, int n){
  int i = blockIdx.x*256 + threadIdx.x;
  if (i < n){
    float v = in[i];
    uint32_t h = bf16hi_rne(__float_as_uint(v));
    float r = v - __uint_as_float(h);
    hi[i] = (uint16_t)(h >> 16);
    lo[i] = (uint16_t)(bf16hi_rne(__float_as_uint(r)) >> 16);
  }
}

__global__ void pack_x(const float* __restrict__ in, uint32_t* __restrict__ out, int n){
  int i = blockIdx.x*256 + threadIdx.x;
  if (i < n) out[i] = pack_split(in[i]);
}

// ---------- batched split GEMM (pre0 / out): C = unpack(A) @ (Whi+Wlo)^T + bias ----------
__global__ __launch_bounds__(256) void gemm_split(
    const uint32_t* __restrict__ A, const uint16_t* __restrict__ Whi,
    const uint16_t* __restrict__ Wlo, const float* __restrict__ bias,
    float* __restrict__ C, int N, int K)
{
  __shared__ uint32_t Al[128*32];
  __shared__ uint16_t Wh[128*32];
  __shared__ uint16_t Wl[128*32];
  const int tid  = threadIdx.x;
  const int lane = tid & 63;
  const int w    = tid >> 6;
  const int wm   = w >> 1, wn = w & 1;
  const int lr   = lane & 15, kg = lane >> 4;
  const int bm   = blockIdx.x, bn = blockIdx.y;

  const uint32_t* Ag  = A   + (size_t)bm*128*K;
  const uint16_t* Whg = Whi + (size_t)bn*128*K;
  const uint16_t* Wlg = Wlo + (size_t)bn*128*K;

  f32x4 acc[4][4];
#pragma unroll
  for (int i = 0; i < 4; ++i)
#pragma unroll
    for (int j = 0; j < 4; ++j) acc[i][j] = (f32x4){0.f,0.f,0.f,0.f};

  for (int ks = 0; ks < K; ks += 32){
    __syncthreads();
#pragma unroll
    for (int j = 0; j < 4; ++j){
      int c = j*256 + tid;
      int row = c >> 3, kc = c & 7;
      int kcs = kc ^ ((row & 3) << 1);
      gl16(Ag + (size_t)row*K + ks + kcs*4, (char*)Al + c*16);
    }
#pragma unroll
    for (int j = 0; j < 2; ++j){
      int c = j*256 + tid;
      int row = c >> 2, kc = c & 3;
      int kcs = kc ^ (row & 3);
      gl16(Whg + (size_t)row*K + ks + kcs*8, (char*)Wh + c*16);
      gl16(Wlg + (size_t)row*K + ks + kcs*8, (char*)Wl + c*16);
    }
    __syncthreads();

    short8 ah[4], al[4];
#pragma unroll
    for (int mt = 0; mt < 4; ++mt){
      int row = wm*64 + mt*16 + lr;
      int c2  = kg ^ (row & 3);
      const uint32_t* p = &Al[row*32 + c2*8];
      uint4 a0 = *(const uint4*)p;
      uint4 a1 = *(const uint4*)(p + 4);
      Frag8 fh, fl;
      unpack_pair(a0.x, a0.y, fh.u[0], fl.u[0]);
      unpack_pair(a0.z, a0.w, fh.u[1], fl.u[1]);
      unpack_pair(a1.x, a1.y, fh.u[2], fl.u[2]);
      unpack_pair(a1.z, a1.w, fh.u[3], fl.u[3]);
      ah[mt] = fh.s; al[mt] = fl.s;
    }
#pragma unroll
    for (int nt = 0; nt < 4; ++nt){
      int row = wn*64 + nt*16 + lr;
      int kc  = kg ^ (row & 3);
      short8 whf = *(const short8*)&Wh[row*32 + kc*8];
      short8 wlf = *(const short8*)&Wl[row*32 + kc*8];
#pragma unroll
      for (int mt = 0; mt < 4; ++mt){
        acc[mt][nt] = __builtin_amdgcn_mfma_f32_16x16x32_bf16(ah[mt], whf, acc[mt][nt], 0,0,0);
        acc[mt][nt] = __builtin_amdgcn_mfma_f32_16x16x32_bf16(al[mt], whf, acc[mt][nt], 0,0,0);
        acc[mt][nt] = __builtin_amdgcn_mfma_f32_16x16x32_bf16(ah[mt], wlf, acc[mt][nt], 0,0,0);
      }
    }
  }
#pragma unroll
  for (int nt = 0; nt < 4; ++nt){
    int col = bn*128 + wn*64 + nt*16 + lr;
    float bv = bias[col];
#pragma unroll
    for (int mt = 0; mt < 4; ++mt){
#pragma unroll
      for (int r = 0; r < 4; ++r){
        int rowg = bm*128 + wm*64 + mt*16 + kg*4 + r;
        C[(size_t)rowg*N + col] = acc[mt][nt][r] + bv;
      }
    }
  }
}

// ---------- persistent wavefront scan: barrier-free wave-private staging ----------
// 192 WGs x 256 thr. group = wg/64: 0 = L0 rec (t=r), 1 = Wih1*h0 (t=r-1),
// 2 = L1 rec (t=r-2). sub=wg%64: rh=sub>>5 (32-row half), ci=sub&31 (32-col).
// Wave w: mt=w&1 (16-row half), kh=w>>1 (K-half). Each wave computes BOTH
// ntw col-tiles for its rows over its K-half -> per-wave A slice (16x512,
// 32 KB) is DISJOINT; staged into a PRIVATE 8 KB dbuf (2x4KB chunks) with
// per-wave counted vmcnt - NO barriers in the chunk loop. kh-pairs reduce
// partials through LDS at round end: only 2 s_barriers per round.
__global__ __launch_bounds__(256, 1) void rnn_persist(
    const float* __restrict__ pre0, uint32_t* __restrict__ h0seq,
    uint32_t* __restrict__ pre1, uint32_t* __restrict__ h1seq,
    const uint16_t* __restrict__ Whh0h, const uint16_t* __restrict__ Whh0l,
    const uint16_t* __restrict__ Wih1h, const uint16_t* __restrict__ Wih1l,
    const uint16_t* __restrict__ Whh1h, const uint16_t* __restrict__ Whh1l,
    const float* __restrict__ bhh0, const float* __restrict__ bih1,
    const float* __restrict__ bhh1,
    uint32_t* h0s, uint32_t* h1s,
    uint32_t* ctr, int T, int first)
{
  __shared__ short WhF[32768];          // 64 KB, fragment-linear
  __shared__ short WlF[32768];          // 64 KB
  __shared__ uint32_t Stage[4][2048];   // 4 waves x 8 KB private dbuf = 32 KB
  const int tid  = threadIdx.x;
  const int lane = tid & 63;
  const int w    = tid >> 6;                 // 0..3
  const int mt   = w & 1, kh = w >> 1;
  const int lr   = lane & 15, kg = lane >> 4;
  const int wg   = blockIdx.x;
  const int group = wg / G_WGS;              // 0,1,2
  const int sub  = wg % G_WGS;
  const int rh   = sub >> 5;                 // 0..1 (rows 32*rh)
  const int ci   = sub & 31;                 // 0..31 (cols 32*ci)
  const int col0 = ci * 32;

  // per-producer flag blocks: (group*2+rh)*64 u32 (32 used, 256B apart)
  uint32_t* fmy = ctr + (group*2 + rh)*64;
  uint32_t* f0  = ctr + (0*2 + rh)*64;
  uint32_t* f1  = ctr + (1*2 + rh)*64;
  uint32_t* f2  = ctr + (2*2 + rh)*64;

  const uint16_t* Whg = (group == 0) ? Whh0h : (group == 1) ? Wih1h : Whh1h;
  const uint16_t* Wlg = (group == 0) ? Whh0l : (group == 1) ? Wih1l : Whh1l;

  // ---- stage W slice into LDS once, fragment-linear ----
#pragma unroll
  for (int it = 0; it < 16; ++it){
    int lin = it*256 + tid;          // 0..4095
    int c = lin >> 7, j = lin & 127;
    int dst = (((c >> 4)*32 + (j >> 2))*64 + (j & 3)*16 + (c & 15))*8;
    *(uint4*)&WhF[dst] = *(const uint4*)&Whg[(size_t)(col0 + c)*HID + j*8];
    *(uint4*)&WlF[dst] = *(const uint4*)&Wlg[(size_t)(col0 + c)*HID + j*8];
  }
  __syncthreads();

  // lane constants
  const int p3r = ((lr & 3) << 1) | ((lr >> 2) & 1);   // swizzle of my A row
  const int fb0 = 0*16384 + lane*8;                    // W frag base ntw=0
  const int fb1 = 1*16384 + lane*8;                    // W frag base ntw=1
  const int colA = col0 + 0*16 + lr;
  const int colB = col0 + 1*16 + lr;
  float bvA = 0.f, bvB = 0.f;
  if (group == 0){ bvA = bhh0[colA]; bvB = bhh0[colB]; }
  else if (group == 1){ bvA = bih1[colA] + bhh1[colA]; bvB = bih1[colB] + bhh1[colB]; }

  const int R = T + 2;
  for (int r = 0; r < R; ++r){
    const int t = r - group;
    const bool valid = (t >= 0 && t < T);

    if (valid){
      // ---- each wave polls its dependencies itself (no syncthreads) ----
      if (group == 0){
        if (t > 0) waitflags32(f0, (uint32_t)t);
      } else if (group == 1){
        waitflags32(f0, (uint32_t)(t+1));
      } else {
        waitflags32(f1, (uint32_t)(t+1));
        if (t > 0) waitflags32(f2, (uint32_t)t);
      }
      asm volatile("" ::: "memory");

      const uint32_t* Ap;
      if (group == 0)
        Ap = (t == 0) ? (first ? (const uint32_t*)0 : h0s)
                      : h0seq + (size_t)(t-1)*(BAT*HID);
      else if (group == 1)
        Ap = h0seq + (size_t)t*(BAT*HID);
      else
        Ap = (t == 0) ? (first ? (const uint32_t*)0 : h1s)
                      : h1seq + (size_t)(t-1)*(BAT*HID);

      // hoisted epilogue-input loads (kh0 waves only; overlap with DMA)
      const int rowb = rh*32 + mt*16 + kg*4;
      const size_t idxA = (size_t)t*(BAT*HID) + (size_t)rowb*HID + colA;
      const size_t idxB = (size_t)t*(BAT*HID) + (size_t)rowb*HID + colB;
      float pvA[4] = {0,0,0,0}, pvB[4] = {0,0,0,0};
      if (kh == 0){
        if (group == 0){
#pragma unroll
          for (int q = 0; q < 4; ++q){ pvA[q] = pre0[idxA + (size_t)q*HID];
                                       pvB[q] = pre0[idxB + (size_t)q*HID]; }
        } else if (group == 2){
#pragma unroll
          for (int q = 0; q < 4; ++q){ pvA[q] = __uint_as_float(pre1[idxA + (size_t)q*HID]);
                                       pvB[q] = __uint_as_float(pre1[idxB + (size_t)q*HID]); }
        }
      }

      f32x4 acc[2][2];   // [ntw][ksl-chain]
#pragma unroll
      for (int i = 0; i < 2; ++i)
#pragma unroll
        for (int j = 0; j < 2; ++j) acc[i][j] = (f32x4){0.f,0.f,0.f,0.f};

      if (Ap){
        // wave-private chunk c (0..7): rows [rh*32+mt*16,+16) x K [kh*512+c*64,+64)
        // slot s = row*16 + pos (16B units); src pos ^= p3(row). 4 gl16/chunk.
        const uint32_t* Aw = Ap + (size_t)(rh*32 + mt*16)*HID + kh*512;
        auto STAGE = [&](int c){
          char* dstbase = (char*)&Stage[w][(c & 1)*1024];
#pragma unroll
          for (int j = 0; j < 4; ++j){
            const int slot  = j*64 + lane;
            const int row_l = slot >> 4;
            const int pos   = slot & 15;
            const int p3 = ((row_l & 3) << 1) | ((row_l >> 2) & 1);
            gl16(Aw + (size_t)row_l*HID + c*64 + (pos ^ p3)*4,
                 dstbase + j*1024 + lane*16);
          }
        };

        STAGE(0); STAGE(1);
#pragma unroll
        for (int c = 0; c < 8; ++c){
          if (c < 7) asm volatile("s_waitcnt vmcnt(8)" ::: "memory");
          else       asm volatile("s_waitcnt vmcnt(0)" ::: "memory");
          // note: vmcnt(8) keeps next chunk (4) + possibly pv (4) in flight;
          // chunk c's 4 loads are complete at vmcnt(8) only if issued order
          // guarantees ">=8 newer" - enforce by issuing STAGE(c+2) AFTER wait.
          const uint32_t* Ab = &Stage[w][(c & 1)*1024 + lr*64];
#pragma unroll
          for (int ksl = 0; ksl < 2; ++ksl){
            const int p0 = (ksl*8 + kg*2) ^ p3r;
            uint4 a0 = *(const uint4*)&Ab[p0*4];
            uint4 a1 = *(const uint4*)&Ab[(p0^1)*4];
            Frag8 fh, fl;
            unpack_pair(a0.x, a0.y, fh.u[0], fl.u[0]);
            unpack_pair(a0.z, a0.w, fh.u[1], fl.u[1]);
            unpack_pair(a1.x, a1.y, fh.u[2], fl.u[2]);
            unpack_pair(a1.z, a1.w, fh.u[3], fl.u[3]);
            const int ks = kh*16 + c*2 + ksl;
            short8 wh0 = *(const short8*)&WhF[fb0 + ks*512];
            short8 wl0 = *(const short8*)&WlF[fb0 + ks*512];
            short8 wh1 = *(const short8*)&WhF[fb1 + ks*512];
            short8 wl1 = *(const short8*)&WlF[fb1 + ks*512];
            acc[0][ksl] = __builtin_amdgcn_mfma_f32_16x16x32_bf16(fh.s, wh0, acc[0][ksl], 0,0,0);
            acc[0][ksl] = __builtin_amdgcn_mfma_f32_16x16x32_bf16(fl.s, wh0, acc[0][ksl], 0,0,0);
            acc[0][ksl] = __builtin_amdgcn_mfma_f32_16x16x32_bf16(fh.s, wl0, acc[0][ksl], 0,0,0);
            acc[1][ksl] = __builtin_amdgcn_mfma_f32_16x16x32_bf16(fh.s, wh1, acc[1][ksl], 0,0,0);
            acc[1][ksl] = __builtin_amdgcn_mfma_f32_16x16x32_bf16(fl.s, wh1, acc[1][ksl], 0,0,0);
            acc[1][ksl] = __builtin_amdgcn_mfma_f32_16x16x32_bf16(fh.s, wl1, acc[1][ksl], 0,0,0);
          }
          if (c < 6) STAGE(c+2);
        }
      }
      f32x4 sA = acc[0][0] + acc[0][1];
      f32x4 sB = acc[1][0] + acc[1][1];

      // ---- kh-pair reduction through LDS (2 barriers total) ----
      if (kh == 1){
        *(f32x4*)&Stage[w][lane*8]     = sA;
        *(f32x4*)&Stage[w][lane*8 + 4] = sB;
        asm volatile("s_waitcnt lgkmcnt(0)" ::: "memory");
      }
      __builtin_amdgcn_s_barrier();          // A: partials visible
      if (kh == 0){
        const int pw = w + 2;
        sA += *(const f32x4*)&Stage[pw][lane*8];
        sB += *(const f32x4*)&Stage[pw][lane*8 + 4];
        // ---- epilogue (both ntw tiles) ----
        if (group == 0){
#pragma unroll
          for (int q = 0; q < 4; ++q){
            float vA = tanhf(sA[q] + pvA[q] + bvA);
            float vB = tanhf(sB[q] + pvB[q] + bvB);
            uint32_t pA = pack_split(vA), pB = pack_split(vB);
            astore32(h0seq + idxA + (size_t)q*HID, pA);
            astore32(h0seq + idxB + (size_t)q*HID, pB);
            if (t == T-1){
              astore32(h0s + (size_t)(rowb + q)*HID + colA, pA);
              astore32(h0s + (size_t)(rowb + q)*HID + colB, pB);
            }
          }
        } else if (group == 1){
#pragma unroll
          for (int q = 0; q < 4; ++q){
            astore32(pre1 + idxA + (size_t)q*HID, __float_as_uint(sA[q] + bvA));
            astore32(pre1 + idxB + (size_t)q*HID, __float_as_uint(sB[q] + bvB));
          }
        } else {
#pragma unroll
          for (int q = 0; q < 4; ++q){
            float vA = tanhf(sA[q] + pvA[q]);
            float vB = tanhf(sB[q] + pvB[q]);
            uint32_t pA = pack_split(vA), pB = pack_split(vB);
            astore32(h1seq + idxA + (size_t)q*HID, pA);
            astore32(h1seq + idxB + (size_t)q*HID, pB);
            if (t == T-1){
              astore32(h1s + (size_t)(rowb + q)*HID + colA, pA);
              astore32(h1s + (size_t)(rowb + q)*HID + colB, pB);
            }
          }
        }
        asm volatile("s_waitcnt vmcnt(0)" ::: "memory");   // drain my stores
      }
      __builtin_amdgcn_s_barrier();          // B: stores drained, slots reusable
      if (tid == 0)
        astore32(fmy + ci, (uint32_t)(t + 1));
    }
  }
}

// ---------- hidden output from carried states ----------
__global__ void extract_hidden(const uint32_t* __restrict__ h0s,
                               const uint32_t* __restrict__ h1s,
                               float* __restrict__ out){
  int i = blockIdx.x*256 + threadIdx.x;   // 0..131071
  uint32_t p = (i >> 16) ? h1s[i & 65535] : h0s[i & 65535];
  out[(size_t)SB*INF + i] = __uint_as_float(p & 0xFFFF0000u) + __uint_as_float(p << 16);
}

// ---------- host ----------
extern "C" void kernel_launch(void* const* d_in, const int* in_sizes, int n_in,
                              void* d_out, int out_size, void* d_ws, size_t ws_size,
                              hipStream_t stream)
{
  const float* x    = (const float*)d_in[0];
  const float* W_in = (const float*)d_in[1];
  const float* b_in = (const float*)d_in[2];
  const float* W_ih = (const float*)d_in[3];   // [2][H][H]
  const float* W_hh = (const float*)d_in[4];   // [2][H][H]
  const float* b_ih = (const float*)d_in[5];   // [2][H]
  const float* b_hh = (const float*)d_in[6];   // [2][H]
  const float* W_out= (const float*)d_in[7];   // [I][H]
  const float* b_out= (const float*)d_in[8];
  float* out = (float*)d_out;
  (void)in_sizes; (void)n_in; (void)out_size;

  // ---- choose chunk length T to fit ws_size ----
  const size_t fixedB = 16257024 + 16384;
  const size_t perT   = 1114112;
  int T = 512;
  while (T > 2 && fixedB + (size_t)T*perT + 65536 > ws_size) T >>= 1;
  const int nchunk = SEQ / T;

  char* ws = (char*)d_ws;
  size_t off = 0;
  auto alloc = [&](size_t bytes)->void*{
    void* p = ws + off; off += (bytes + 255) & ~(size_t)255; return p;
  };
  float*    pre0s  = (float*)   alloc((size_t)T*BAT*HID*4);
  uint32_t* h0seq  = (uint32_t*)alloc((size_t)T*BAT*HID*4);
  uint32_t* pre1s  = (uint32_t*)alloc((size_t)T*BAT*HID*4);
  uint32_t* h1seq  = (uint32_t*)alloc((size_t)T*BAT*HID*4);
  uint32_t* xp     = (uint32_t*)alloc((size_t)T*BAT*INF*4);
  float*    WcombF = (float*)   alloc((size_t)HID*INF*4);
  uint16_t* Wc_hi  = (uint16_t*)alloc((size_t)HID*INF*2);
  uint16_t* Wc_lo  = (uint16_t*)alloc((size_t)HID*INF*2);
  uint16_t* Wih1_hi= (uint16_t*)alloc((size_t)HID*HID*2);
  uint16_t* Wih1_lo= (uint16_t*)alloc((size_t)HID*HID*2);
  uint16_t* Whh0_hi= (uint16_t*)alloc((size_t)HID*HID*2);
  uint16_t* Whh0_lo= (uint16_t*)alloc((size_t)HID*HID*2);
  uint16_t* Whh1_hi= (uint16_t*)alloc((size_t)HID*HID*2);
  uint16_t* Whh1_lo= (uint16_t*)alloc((size_t)HID*HID*2);
  uint16_t* Wout_hi= (uint16_t*)alloc((size_t)INF*HID*2);
  uint16_t* Wout_lo= (uint16_t*)alloc((size_t)INF*HID*2);
  float*    bcomb  = (float*)   alloc((size_t)HID*4);
  uint32_t* h0s    = (uint32_t*)alloc((size_t)BAT*HID*4);
  uint32_t* h1s    = (uint32_t*)alloc((size_t)BAT*HID*4);
  uint32_t* ctr    = (uint32_t*)alloc(8192);

  // ---- prep ----
  wcomb_kernel<<<HID/16, 256, 0, stream>>>(W_ih, W_in, WcombF);
  bcomb_kernel<<<HID, 256, 0, stream>>>(W_ih, b_in, b_ih, bcomb);
  split_w<<<(HID*INF+255)/256, 256, 0, stream>>>(WcombF, Wc_hi, Wc_lo, HID*INF);
  split_w<<<(HID*HID+255)/256, 256, 0, stream>>>(W_ih + (size_t)HID*HID, Wih1_hi, Wih1_lo, HID*HID);
  split_w<<<(HID*HID+255)/256, 256, 0, stream>>>(W_hh, Whh0_hi, Whh0_lo, HID*HID);
  split_w<<<(HID*HID+255)/256, 256, 0, stream>>>(W_hh + (size_t)HID*HID, Whh1_hi, Whh1_lo, HID*HID);
  split_w<<<(INF*HID+255)/256, 256, 0, stream>>>(W_out, Wout_hi, Wout_lo, INF*HID);

  // ---- chunked pipeline ----
  for (int c = 0; c < nchunk; ++c){
    const float* xc = x + (size_t)c*T*BAT*INF;
    pack_x<<<T*BAT*INF/256, 256, 0, stream>>>(xc, xp, T*BAT*INF);
    // pre0 chunk = xp @ Wcomb^T + bcomb
    gemm_split<<<dim3(T*64/128, HID/128), 256, 0, stream>>>(xp, Wc_hi, Wc_lo, bcomb, pre0s, HID, INF);
    // wavefront scan over the chunk (both layers + pre1 fused)
    hipMemsetAsync(ctr, 0, 8192, stream);
    rnn_persist<<<NWG, 256, 0, stream>>>(
        pre0s, h0seq, pre1s, h1seq,
        Whh0_hi, Whh0_lo, Wih1_hi, Wih1_lo, Whh1_hi, Whh1_lo,
        b_hh, b_ih + HID, b_hh + HID, h0s, h1s, ctr, T, (c == 0) ? 1 : 0);
    // out chunk = h1chunk @ Wout^T + b_out
    gemm_split<<<dim3(T*64/128, INF/128), 256, 0, stream>>>(h1seq, Wout_hi, Wout_lo,
                                                            b_out, out + (size_t)c*T*BAT*INF, INF, HID);
  }
  extract_hidden<<<(2*BAT*HID)/256, 256, 0, stream>>>(h0s, h1s, out);
}

// Round 16
// 4704.515 us; speedup vs baseline: 1.2245x; 1.0233x over previous
//
#include <hip/hip_runtime.h>
#include <stdint.h>

#define SEQ 512
#define BAT 64
#define INF 256     // input features
#define HID 1024
#define SB  (SEQ*BAT)   // 32768 rows
#define G_WGS 64            // WGs per pipeline group
#define NWG (3*G_WGS)       // 192 persistent WGs

typedef __attribute__((ext_vector_type(8))) short short8;
typedef __attribute__((ext_vector_type(4))) float f32x4;

union Frag8 { uint32_t u[4]; short8 s; };

// ---------- numeric helpers: fp32 <-> (bf16 hi, bf16 lo) ----------
__device__ __forceinline__ uint32_t bf16hi_rne(uint32_t u){
  return (u + 0x7FFFu + ((u >> 16) & 1u)) & 0xFFFF0000u;
}
__device__ __forceinline__ uint32_t pack_split(float v){
  uint32_t hi = bf16hi_rne(__float_as_uint(v));
  float r = v - __uint_as_float(hi);
  uint32_t lo = bf16hi_rne(__float_as_uint(r)) >> 16;
  return hi | lo;                              // (hi16<<16) | lo16
}
__device__ __forceinline__ void unpack_pair(uint32_t u0, uint32_t u1,
                                            uint32_t& h, uint32_t& l){
  h = __builtin_amdgcn_perm(u1, u0, 0x07060302u);  // {u0.b2,u0.b3,u1.b2,u1.b3}
  l = __builtin_amdgcn_perm(u1, u0, 0x05040100u);  // {u0.b0,u0.b1,u1.b0,u1.b1}
}
__device__ __forceinline__ void gl16(const void* g, void* l){
  __builtin_amdgcn_global_load_lds(
      (const __attribute__((address_space(1))) void*)g,
      (__attribute__((address_space(3))) void*)l, 16, 0, 0);
}

// ---------- agent-scope atomics (flags + cross-WG visible writes) ----------
__device__ __forceinline__ void astore32(uint32_t* p, uint32_t v){
  __hip_atomic_store(p, v, __ATOMIC_RELAXED, __HIP_MEMORY_SCOPE_AGENT);
}
// wave-cooperative poll: lanes 0..31 each watch one producer flag
__device__ __forceinline__ void waitflags32(const uint32_t* base, uint32_t tgt){
  const int lane = threadIdx.x & 63;
  unsigned spins = 0;
  for (;;){
    uint32_t v = (lane < 32)
        ? __hip_atomic_load(base + lane, __ATOMIC_RELAXED, __HIP_MEMORY_SCOPE_AGENT)
        : 0xFFFFFFFFu;
    if (__all(v >= tgt)) break;
    __builtin_amdgcn_s_sleep(1);
    if (++spins > (1u << 20)) break;   // failsafe: fail fast, never wedge
  }
}

// ---------- prep kernels ----------
__global__ __launch_bounds__(256) void wcomb_kernel(const float* __restrict__ A,
                                                    const float* __restrict__ B,
                                                    float* __restrict__ C){
  __shared__ float As[16][64];
  __shared__ float Bs[64][256];
  const int tid = threadIdx.x;
  const int g0 = blockIdx.x * 16;
  float acc[16];
#pragma unroll
  for (int g = 0; g < 16; ++g) acc[g] = 0.f;
  for (int h0 = 0; h0 < HID; h0 += 64){
    __syncthreads();
#pragma unroll
    for (int j = 0; j < 4; ++j){
      int c = j*256 + tid;
      As[c >> 6][c & 63] = A[(size_t)(g0 + (c >> 6))*HID + h0 + (c & 63)];
    }
#pragma unroll
    for (int j = 0; j < 64; ++j) Bs[j][tid] = B[(size_t)(h0 + j)*INF + tid];
    __syncthreads();
#pragma unroll
    for (int hh = 0; hh < 64; hh += 4){
      float b0 = Bs[hh][tid], b1 = Bs[hh+1][tid], b2 = Bs[hh+2][tid], b3 = Bs[hh+3][tid];
#pragma unroll
      for (int g = 0; g < 16; ++g){
        const float4 a = *(const float4*)&As[g][hh];
        acc[g] += a.x*b0 + a.y*b1 + a.z*b2 + a.w*b3;
      }
    }
  }
#pragma unroll
  for (int g = 0; g < 16; ++g) C[(size_t)(g0 + g)*INF + tid] = acc[g];
}

__global__ __launch_bounds__(256) void bcomb_kernel(const float* __restrict__ Wih0,
                                                    const float* __restrict__ bin,
                                                    const float* __restrict__ bih0,
                                                    float* __restrict__ bcomb){
  __shared__ float r[4];
  const int g = blockIdx.x, tid = threadIdx.x;
  float s = 0.f;
  for (int h = tid; h < HID; h += 256) s += Wih0[(size_t)g*HID + h] * bin[h];
  for (int o = 32; o > 0; o >>= 1) s += __shfl_down(s, o, 64);
  if ((tid & 63) == 0) r[tid >> 6] = s;
  __syncthreads();
  if (tid == 0) bcomb[g] = bih0[g] + r[0] + r[1] + r[2] + r[3];
}

__global__ void split_w(const float* __restrict__ in, uint16_t* __restrict__ hi,
                        uint16_t* __restrict__ lo, int n){
  int i = blockIdx.x*256 + threadIdx.x;
  if (i < n){
    float v = in[i];
    uint32_t h = bf16hi_rne(__float_as_uint(v));
    float r = v - __uint_as_float(h);
    hi[i] = (uint16_t)(h >> 16);
    lo[i] = (uint16_t)(bf16hi_rne(__float_as_uint(r)) >> 16);
  }
}

__global__ void pack_x(const float* __restrict__ in, uint32_t* __restrict__ out, int n){
  int i = blockIdx.x*256 + threadIdx.x;
  if (i < n) out[i] = pack_split(in[i]);
}

// ---------- batched split GEMM (pre0 / out): C = unpack(A) @ (Whi+Wlo)^T + bias ----------
__global__ __launch_bounds__(256) void gemm_split(
    const uint32_t* __restrict__ A, const uint16_t* __restrict__ Whi,
    const uint16_t* __restrict__ Wlo, const float* __restrict__ bias,
    float* __restrict__ C, int N, int K)
{
  __shared__ uint32_t Al[128*32];
  __shared__ uint16_t Wh[128*32];
  __shared__ uint16_t Wl[128*32];
  const int tid  = threadIdx.x;
  const int lane = tid & 63;
  const int w    = tid >> 6;
  const int wm   = w >> 1, wn = w & 1;
  const int lr   = lane & 15, kg = lane >> 4;
  const int bm   = blockIdx.x, bn = blockIdx.y;

  const uint32_t* Ag  = A   + (size_t)bm*128*K;
  const uint16_t* Whg = Whi + (size_t)bn*128*K;
  const uint16_t* Wlg = Wlo + (size_t)bn*128*K;

  f32x4 acc[4][4];
#pragma unroll
  for (int i = 0; i < 4; ++i)
#pragma unroll
    for (int j = 0; j < 4; ++j) acc[i][j] = (f32x4){0.f,0.f,0.f,0.f};

  for (int ks = 0; ks < K; ks += 32){
    __syncthreads();
#pragma unroll
    for (int j = 0; j < 4; ++j){
      int c = j*256 + tid;
      int row = c >> 3, kc = c & 7;
      int kcs = kc ^ ((row & 3) << 1);
      gl16(Ag + (size_t)row*K + ks + kcs*4, (char*)Al + c*16);
    }
#pragma unroll
    for (int j = 0; j < 2; ++j){
      int c = j*256 + tid;
      int row = c >> 2, kc = c & 3;
      int kcs = kc ^ (row & 3);
      gl16(Whg + (size_t)row*K + ks + kcs*8, (char*)Wh + c*16);
      gl16(Wlg + (size_t)row*K + ks + kcs*8, (char*)Wl + c*16);
    }
    __syncthreads();

    short8 ah[4], al[4];
#pragma unroll
    for (int mt = 0; mt < 4; ++mt){
      int row = wm*64 + mt*16 + lr;
      int c2  = kg ^ (row & 3);
      const uint32_t* p = &Al[row*32 + c2*8];
      uint4 a0 = *(const uint4*)p;
      uint4 a1 = *(const uint4*)(p + 4);
      Frag8 fh, fl;
      unpack_pair(a0.x, a0.y, fh.u[0], fl.u[0]);
      unpack_pair(a0.z, a0.w, fh.u[1], fl.u[1]);
      unpack_pair(a1.x, a1.y, fh.u[2], fl.u[2]);
      unpack_pair(a1.z, a1.w, fh.u[3], fl.u[3]);
      ah[mt] = fh.s; al[mt] = fl.s;
    }
#pragma unroll
    for (int nt = 0; nt < 4; ++nt){
      int row = wn*64 + nt*16 + lr;
      int kc  = kg ^ (row & 3);
      short8 whf = *(const short8*)&Wh[row*32 + kc*8];
      short8 wlf = *(const short8*)&Wl[row*32 + kc*8];
#pragma unroll
      for (int mt = 0; mt < 4; ++mt){
        acc[mt][nt] = __builtin_amdgcn_mfma_f32_16x16x32_bf16(ah[mt], whf, acc[mt][nt], 0,0,0);
        acc[mt][nt] = __builtin_amdgcn_mfma_f32_16x16x32_bf16(al[mt], whf, acc[mt][nt], 0,0,0);
        acc[mt][nt] = __builtin_amdgcn_mfma_f32_16x16x32_bf16(ah[mt], wlf, acc[mt][nt], 0,0,0);
      }
    }
  }
#pragma unroll
  for (int nt = 0; nt < 4; ++nt){
    int col = bn*128 + wn*64 + nt*16 + lr;
    float bv = bias[col];
#pragma unroll
    for (int mt = 0; mt < 4; ++mt){
#pragma unroll
      for (int r = 0; r < 4; ++r){
        int rowg = bm*128 + wm*64 + mt*16 + kg*4 + r;
        C[(size_t)rowg*N + col] = acc[mt][nt][r] + bv;
      }
    }
  }
}

// ---------- persistent wavefront scan: airtight dbuf + split epilogue ----------
// 192 WGs x 256 thr. group = wg/64: 0 = L0 rec (t=r), 1 = Wih1*h0 (t=r-1),
// 2 = L1 rec (t=r-2). sub=wg%64: rh=sub>>5 (rows 32*rh), ci=sub&31 (cols 32*ci).
// Wave w: mt=w&1 (16-row half), kh=w>>1 (K-half). Per-wave A slice (16x512)
// staged into private 8 KB dbuf; schedule: STAGE(c+1) -> vmcnt(4) -> compute c
// (chunk c guaranteed landed; c+1 in the other slot, in flight - no clobber
// window). Round-start rendezvous via wave-wide flag polls (round-14 proven).
// kh-partners exchange partials through LDS both ways; kh0 finishes colA,
// kh1 colB (split epilogue). 2 s_barriers per round.
__global__ __launch_bounds__(256, 1) void rnn_persist(
    const float* __restrict__ pre0, uint32_t* __restrict__ h0seq,
    uint32_t* __restrict__ pre1, uint32_t* __restrict__ h1seq,
    const uint16_t* __restrict__ Whh0h, const uint16_t* __restrict__ Whh0l,
    const uint16_t* __restrict__ Wih1h, const uint16_t* __restrict__ Wih1l,
    const uint16_t* __restrict__ Whh1h, const uint16_t* __restrict__ Whh1l,
    const float* __restrict__ bhh0, const float* __restrict__ bih1,
    const float* __restrict__ bhh1,
    uint32_t* h0s, uint32_t* h1s,
    uint32_t* ctr, int T, int first)
{
  __shared__ short WhF[32768];          // 64 KB, fragment-linear
  __shared__ short WlF[32768];          // 64 KB
  __shared__ uint32_t Stage[4][2048];   // 4 waves x 8 KB private dbuf = 32 KB
  const int tid  = threadIdx.x;
  const int lane = tid & 63;
  const int w    = tid >> 6;                 // 0..3
  const int mt   = w & 1, kh = w >> 1;
  const int lr   = lane & 15, kg = lane >> 4;
  const int wg   = blockIdx.x;
  const int group = wg / G_WGS;              // 0,1,2
  const int sub  = wg % G_WGS;
  const int rh   = sub >> 5;                 // rows 32*rh
  const int ci   = sub & 31;                 // cols 32*ci
  const int col0 = ci * 32;

  // per-producer flag blocks: (group*2+rh)*64 u32 (32 used)
  uint32_t* fmy = ctr + (group*2 + rh)*64;
  uint32_t* f0  = ctr + (0*2 + rh)*64;
  uint32_t* f1  = ctr + (1*2 + rh)*64;
  uint32_t* f2  = ctr + (2*2 + rh)*64;

  const uint16_t* Whg = (group == 0) ? Whh0h : (group == 1) ? Wih1h : Whh1h;
  const uint16_t* Wlg = (group == 0) ? Whh0l : (group == 1) ? Wih1l : Whh1l;

  // ---- stage W slice into LDS once, fragment-linear ----
#pragma unroll
  for (int it = 0; it < 16; ++it){
    int lin = it*256 + tid;          // 0..4095
    int c = lin >> 7, j = lin & 127;
    int dst = (((c >> 4)*32 + (j >> 2))*64 + (j & 3)*16 + (c & 15))*8;
    *(uint4*)&WhF[dst] = *(const uint4*)&Whg[(size_t)(col0 + c)*HID + j*8];
    *(uint4*)&WlF[dst] = *(const uint4*)&Wlg[(size_t)(col0 + c)*HID + j*8];
  }
  __syncthreads();

  // lane constants
  const int p3r = ((lr & 3) << 1) | ((lr >> 2) & 1);   // swizzle of my A row
  const int fb0 = 0*16384 + lane*8;                    // W frag base ntw=0 (colA)
  const int fb1 = 1*16384 + lane*8;                    // W frag base ntw=1 (colB)
  const int colE = col0 + kh*16 + lr;                  // my epilogue column (kh0->A, kh1->B)
  float bvE = 0.f;
  if (group == 0) bvE = bhh0[colE];
  else if (group == 1) bvE = bih1[colE] + bhh1[colE];

  const int R = T + 2;
  for (int r = 0; r < R; ++r){
    const int t = r - group;
    const bool valid = (t >= 0 && t < T);

    if (valid){
      // ---- round-start rendezvous: each wave polls its own dependencies ----
      if (group == 0){
        if (t > 0) waitflags32(f0, (uint32_t)t);
      } else if (group == 1){
        waitflags32(f0, (uint32_t)(t+1));
      } else {
        waitflags32(f1, (uint32_t)(t+1));
        if (t > 0) waitflags32(f2, (uint32_t)t);
      }
      asm volatile("" ::: "memory");

      const uint32_t* Ap;
      if (group == 0)
        Ap = (t == 0) ? (first ? (const uint32_t*)0 : h0s)
                      : h0seq + (size_t)(t-1)*(BAT*HID);
      else if (group == 1)
        Ap = h0seq + (size_t)t*(BAT*HID);
      else
        Ap = (t == 0) ? (first ? (const uint32_t*)0 : h1s)
                      : h1seq + (size_t)(t-1)*(BAT*HID);

      // ---- epilogue-input (pv) loads for my column tile (issued first) ----
      const int rowb = rh*32 + mt*16 + kg*4;
      const size_t idxE = (size_t)t*(BAT*HID) + (size_t)rowb*HID + colE;
      float pv[4] = {0,0,0,0};
      if (group == 0){
#pragma unroll
        for (int q = 0; q < 4; ++q) pv[q] = pre0[idxE + (size_t)q*HID];
      } else if (group == 2){
#pragma unroll
        for (int q = 0; q < 4; ++q) pv[q] = __uint_as_float(pre1[idxE + (size_t)q*HID]);
      }

      f32x4 acc[2][2];   // [ntw][ksl-chain]
#pragma unroll
      for (int i = 0; i < 2; ++i)
#pragma unroll
        for (int j = 0; j < 2; ++j) acc[i][j] = (f32x4){0.f,0.f,0.f,0.f};

      if (Ap){
        const uint32_t* Aw = Ap + (size_t)(rh*32 + mt*16)*HID + kh*512;
        auto STAGE = [&](int c){
          char* dstbase = (char*)&Stage[w][(c & 1)*1024];
#pragma unroll
          for (int j = 0; j < 4; ++j){
            const int slot  = j*64 + lane;
            const int row_l = slot >> 4;
            const int pos   = slot & 15;
            const int p3 = ((row_l & 3) << 1) | ((row_l >> 2) & 1);
            gl16(Aw + (size_t)row_l*HID + c*64 + (pos ^ p3)*4,
                 dstbase + j*1024 + lane*16);
          }
        };

        STAGE(0);
#pragma unroll
        for (int c = 0; c < 8; ++c){
          if (c < 7){
            STAGE(c+1);                                   // other slot, in flight
            asm volatile("s_waitcnt vmcnt(4)" ::: "memory");  // chunk c landed
          } else {
            asm volatile("s_waitcnt vmcnt(0)" ::: "memory");
          }
          const uint32_t* Ab = &Stage[w][(c & 1)*1024 + lr*64];
#pragma unroll
          for (int ksl = 0; ksl < 2; ++ksl){
            const int p0 = (ksl*8 + kg*2) ^ p3r;
            uint4 a0 = *(const uint4*)&Ab[p0*4];
            uint4 a1 = *(const uint4*)&Ab[(p0^1)*4];
            Frag8 fh, fl;
            unpack_pair(a0.x, a0.y, fh.u[0], fl.u[0]);
            unpack_pair(a0.z, a0.w, fh.u[1], fl.u[1]);
            unpack_pair(a1.x, a1.y, fh.u[2], fl.u[2]);
            unpack_pair(a1.z, a1.w, fh.u[3], fl.u[3]);
            const int ks = kh*16 + c*2 + ksl;
            short8 wh0 = *(const short8*)&WhF[fb0 + ks*512];
            short8 wl0 = *(const short8*)&WlF[fb0 + ks*512];
            short8 wh1 = *(const short8*)&WhF[fb1 + ks*512];
            short8 wl1 = *(const short8*)&WlF[fb1 + ks*512];
            acc[0][ksl] = __builtin_amdgcn_mfma_f32_16x16x32_bf16(fh.s, wh0, acc[0][ksl], 0,0,0);
            acc[0][ksl] = __builtin_amdgcn_mfma_f32_16x16x32_bf16(fl.s, wh0, acc[0][ksl], 0,0,0);
            acc[0][ksl] = __builtin_amdgcn_mfma_f32_16x16x32_bf16(fh.s, wl0, acc[0][ksl], 0,0,0);
            acc[1][ksl] = __builtin_amdgcn_mfma_f32_16x16x32_bf16(fh.s, wh1, acc[1][ksl], 0,0,0);
            acc[1][ksl] = __builtin_amdgcn_mfma_f32_16x16x32_bf16(fl.s, wh1, acc[1][ksl], 0,0,0);
            acc[1][ksl] = __builtin_amdgcn_mfma_f32_16x16x32_bf16(fh.s, wl1, acc[1][ksl], 0,0,0);
          }
        }
      }
      f32x4 sA = acc[0][0] + acc[0][1];   // my partial, colA tile
      f32x4 sB = acc[1][0] + acc[1][1];   // my partial, colB tile

      // ---- symmetric partial exchange: kh0 gives sB, kh1 gives sA ----
      {
        f32x4 give = (kh == 0) ? sB : sA;
        *(f32x4*)&Stage[w][lane*8] = give;
        asm volatile("s_waitcnt lgkmcnt(0)" ::: "memory");
      }
      __builtin_amdgcn_s_barrier();          // A: partials visible
      {
        const int pw = w ^ 2;
        f32x4 part = *(const f32x4*)&Stage[pw][lane*8];
        f32x4 sE = (kh == 0) ? (sA + part) : (part + sB);

        // ---- split epilogue: this wave stores its own col tile ----
        if (group == 0){
#pragma unroll
          for (int q = 0; q < 4; ++q){
            float v = tanhf(sE[q] + pv[q] + bvE);
            uint32_t pk = pack_split(v);
            astore32(h0seq + idxE + (size_t)q*HID, pk);
            if (t == T-1) astore32(h0s + (size_t)(rowb + q)*HID + colE, pk);
          }
        } else if (group == 1){
#pragma unroll
          for (int q = 0; q < 4; ++q)
            astore32(pre1 + idxE + (size_t)q*HID, __float_as_uint(sE[q] + bvE));
        } else {
#pragma unroll
          for (int q = 0; q < 4; ++q){
            float v = tanhf(sE[q] + pv[q]);
            uint32_t pk = pack_split(v);
            astore32(h1seq + idxE + (size_t)q*HID, pk);
            if (t == T-1) astore32(h1s + (size_t)(rowb + q)*HID + colE, pk);
          }
        }
        asm volatile("s_waitcnt vmcnt(0)" ::: "memory");   // drain my stores
      }
      __builtin_amdgcn_s_barrier();          // B: all stores drained, slots reusable
      if (tid == 0)
        astore32(fmy + ci, (uint32_t)(t + 1));
    }
  }
}

// ---------- hidden output from carried states ----------
__global__ void extract_hidden(const uint32_t* __restrict__ h0s,
                               const uint32_t* __restrict__ h1s,
                               float* __restrict__ out){
  int i = blockIdx.x*256 + threadIdx.x;   // 0..131071
  uint32_t p = (i >> 16) ? h1s[i & 65535] : h0s[i & 65535];
  out[(size_t)SB*INF + i] = __uint_as_float(p & 0xFFFF0000u) + __uint_as_float(p << 16);
}

// ---------- host ----------
extern "C" void kernel_launch(void* const* d_in, const int* in_sizes, int n_in,
                              void* d_out, int out_size, void* d_ws, size_t ws_size,
                              hipStream_t stream)
{
  const float* x    = (const float*)d_in[0];
  const float* W_in = (const float*)d_in[1];
  const float* b_in = (const float*)d_in[2];
  const float* W_ih = (const float*)d_in[3];   // [2][H][H]
  const float* W_hh = (const float*)d_in[4];   // [2][H][H]
  const float* b_ih = (const float*)d_in[5];   // [2][H]
  const float* b_hh = (const float*)d_in[6];   // [2][H]
  const float* W_out= (const float*)d_in[7];   // [I][H]
  const float* b_out= (const float*)d_in[8];
  float* out = (float*)d_out;
  (void)in_sizes; (void)n_in; (void)out_size;

  // ---- choose chunk length T to fit ws_size ----
  const size_t fixedB = 16257024 + 16384;
  const size_t perT   = 1114112;
  int T = 512;
  while (T > 2 && fixedB + (size_t)T*perT + 65536 > ws_size) T >>= 1;
  const int nchunk = SEQ / T;

  char* ws = (char*)d_ws;
  size_t off = 0;
  auto alloc = [&](size_t bytes)->void*{
    void* p = ws + off; off += (bytes + 255) & ~(size_t)255; return p;
  };
  float*    pre0s  = (float*)   alloc((size_t)T*BAT*HID*4);
  uint32_t* h0seq  = (uint32_t*)alloc((size_t)T*BAT*HID*4);
  uint32_t* pre1s  = (uint32_t*)alloc((size_t)T*BAT*HID*4);
  uint32_t* h1seq  = (uint32_t*)alloc((size_t)T*BAT*HID*4);
  uint32_t* xp     = (uint32_t*)alloc((size_t)T*BAT*INF*4);
  float*    WcombF = (float*)   alloc((size_t)HID*INF*4);
  uint16_t* Wc_hi  = (uint16_t*)alloc((size_t)HID*INF*2);
  uint16_t* Wc_lo  = (uint16_t*)alloc((size_t)HID*INF*2);
  uint16_t* Wih1_hi= (uint16_t*)alloc((size_t)HID*HID*2);
  uint16_t* Wih1_lo= (uint16_t*)alloc((size_t)HID*HID*2);
  uint16_t* Whh0_hi= (uint16_t*)alloc((size_t)HID*HID*2);
  uint16_t* Whh0_lo= (uint16_t*)alloc((size_t)HID*HID*2);
  uint16_t* Whh1_hi= (uint16_t*)alloc((size_t)HID*HID*2);
  uint16_t* Whh1_lo= (uint16_t*)alloc((size_t)HID*HID*2);
  uint16_t* Wout_hi= (uint16_t*)alloc((size_t)INF*HID*2);
  uint16_t* Wout_lo= (uint16_t*)alloc((size_t)INF*HID*2);
  float*    bcomb  = (float*)   alloc((size_t)HID*4);
  uint32_t* h0s    = (uint32_t*)alloc((size_t)BAT*HID*4);
  uint32_t* h1s    = (uint32_t*)alloc((size_t)BAT*HID*4);
  uint32_t* ctr    = (uint32_t*)alloc(8192);

  // ---- prep ----
  wcomb_kernel<<<HID/16, 256, 0, stream>>>(W_ih, W_in, WcombF);
  bcomb_kernel<<<HID, 256, 0, stream>>>(W_ih, b_in, b_ih, bcomb);
  split_w<<<(HID*INF+255)/256, 256, 0, stream>>>(WcombF, Wc_hi, Wc_lo, HID*INF);
  split_w<<<(HID*HID+255)/256, 256, 0, stream>>>(W_ih + (size_t)HID*HID, Wih1_hi, Wih1_lo, HID*HID);
  split_w<<<(HID*HID+255)/256, 256, 0, stream>>>(W_hh, Whh0_hi, Whh0_lo, HID*HID);
  split_w<<<(HID*HID+255)/256, 256, 0, stream>>>(W_hh + (size_t)HID*HID, Whh1_hi, Whh1_lo, HID*HID);
  split_w<<<(INF*HID+255)/256, 256, 0, stream>>>(W_out, Wout_hi, Wout_lo, INF*HID);

  // ---- chunked pipeline ----
  for (int c = 0; c < nchunk; ++c){
    const float* xc = x + (size_t)c*T*BAT*INF;
    pack_x<<<T*BAT*INF/256, 256, 0, stream>>>(xc, xp, T*BAT*INF);
    // pre0 chunk = xp @ Wcomb^T + bcomb
    gemm_split<<<dim3(T*64/128, HID/128), 256, 0, stream>>>(xp, Wc_hi, Wc_lo, bcomb, pre0s, HID, INF);
    // wavefront scan over the chunk (both layers + pre1 fused)
    hipMemsetAsync(ctr, 0, 8192, stream);
    rnn_persist<<<NWG, 256, 0, stream>>>(
        pre0s, h0seq, pre1s, h1seq,
        Whh0_hi, Whh0_lo, Wih1_hi, Wih1_lo, Whh1_hi, Whh1_lo,
        b_hh, b_ih + HID, b_hh + HID, h0s, h1s, ctr, T, (c == 0) ? 1 : 0);
    // out chunk = h1chunk @ Wout^T + b_out
    gemm_split<<<dim3(T*64/128, INF/128), 256, 0, stream>>>(h1seq, Wout_hi, Wout_lo,
                                                            b_out, out + (size_t)c*T*BAT*INF, INF, HID);
  }
  extract_hidden<<<(2*BAT*HID)/256, 256, 0, stream>>>(h0s, h1s, out);
}

// Round 17
// 3858.853 us; speedup vs baseline: 1.4929x; 1.2191x over previous
//
#include <hip/hip_runtime.h>
#include <stdint.h>

#define SEQ 512
#define BAT 64
#define INF 256     // input features
#define HID 1024
#define SB  (SEQ*BAT)   // 32768 rows
#define G_WGS 64            // WGs per pipeline group
#define NWG (3*G_WGS)       // 192 persistent WGs

typedef __attribute__((ext_vector_type(8))) short short8;
typedef __attribute__((ext_vector_type(4))) float f32x4;

// ---------- numeric helpers ----------
__device__ __forceinline__ uint32_t bf16hi_rne(uint32_t u){
  return (u + 0x7FFFu + ((u >> 16) & 1u)) & 0xFFFF0000u;
}
__device__ __forceinline__ uint32_t bf16_of(float v){   // u16 result in low bits
  return bf16hi_rne(__float_as_uint(v)) >> 16;
}
__device__ __forceinline__ void gl16(const void* g, void* l){
  __builtin_amdgcn_global_load_lds(
      (const __attribute__((address_space(1))) void*)g,
      (__attribute__((address_space(3))) void*)l, 16, 0, 0);
}

// ---------- agent-scope atomics (flags + cross-WG visible writes) ----------
__device__ __forceinline__ void astore32(uint32_t* p, uint32_t v){
  __hip_atomic_store(p, v, __ATOMIC_RELAXED, __HIP_MEMORY_SCOPE_AGENT);
}
// wave-cooperative poll: lanes 0..31 each watch one producer flag
__device__ __forceinline__ void waitflags32(const uint32_t* base, uint32_t tgt){
  const int lane = threadIdx.x & 63;
  unsigned spins = 0;
  for (;;){
    uint32_t v = (lane < 32)
        ? __hip_atomic_load(base + lane, __ATOMIC_RELAXED, __HIP_MEMORY_SCOPE_AGENT)
        : 0xFFFFFFFFu;
    if (__all(v >= tgt)) break;
    __builtin_amdgcn_s_sleep(1);
    if (++spins > (1u << 20)) break;   // failsafe: fail fast, never wedge
  }
}

// ---------- prep kernels ----------
__global__ __launch_bounds__(256) void wcomb_kernel(const float* __restrict__ A,
                                                    const float* __restrict__ B,
                                                    float* __restrict__ C){
  __shared__ float As[16][64];
  __shared__ float Bs[64][256];
  const int tid = threadIdx.x;
  const int g0 = blockIdx.x * 16;
  float acc[16];
#pragma unroll
  for (int g = 0; g < 16; ++g) acc[g] = 0.f;
  for (int h0 = 0; h0 < HID; h0 += 64){
    __syncthreads();
#pragma unroll
    for (int j = 0; j < 4; ++j){
      int c = j*256 + tid;
      As[c >> 6][c & 63] = A[(size_t)(g0 + (c >> 6))*HID + h0 + (c & 63)];
    }
#pragma unroll
    for (int j = 0; j < 64; ++j) Bs[j][tid] = B[(size_t)(h0 + j)*INF + tid];
    __syncthreads();
#pragma unroll
    for (int hh = 0; hh < 64; hh += 4){
      float b0 = Bs[hh][tid], b1 = Bs[hh+1][tid], b2 = Bs[hh+2][tid], b3 = Bs[hh+3][tid];
#pragma unroll
      for (int g = 0; g < 16; ++g){
        const float4 a = *(const float4*)&As[g][hh];
        acc[g] += a.x*b0 + a.y*b1 + a.z*b2 + a.w*b3;
      }
    }
  }
#pragma unroll
  for (int g = 0; g < 16; ++g) C[(size_t)(g0 + g)*INF + tid] = acc[g];
}

__global__ __launch_bounds__(256) void bcomb_kernel(const float* __restrict__ Wih0,
                                                    const float* __restrict__ bin,
                                                    const float* __restrict__ bih0,
                                                    float* __restrict__ bcomb){
  __shared__ float r[4];
  const int g = blockIdx.x, tid = threadIdx.x;
  float s = 0.f;
  for (int h = tid; h < HID; h += 256) s += Wih0[(size_t)g*HID + h] * bin[h];
  for (int o = 32; o > 0; o >>= 1) s += __shfl_down(s, o, 64);
  if ((tid & 63) == 0) r[tid >> 6] = s;
  __syncthreads();
  if (tid == 0) bcomb[g] = bih0[g] + r[0] + r[1] + r[2] + r[3];
}

__global__ void split_w(const float* __restrict__ in, uint16_t* __restrict__ hi,
                        uint16_t* __restrict__ lo, int n){
  int i = blockIdx.x*256 + threadIdx.x;
  if (i < n){
    float v = in[i];
    uint32_t h = bf16hi_rne(__float_as_uint(v));
    float r = v - __uint_as_float(h);
    hi[i] = (uint16_t)(h >> 16);
    lo[i] = (uint16_t)(bf16hi_rne(__float_as_uint(r)) >> 16);
  }
}

// f32 -> bf16 pairs (u32 = {bf16 2i (lo), bf16 2i+1 (hi)})
__global__ void pack_xb(const float* __restrict__ in, uint32_t* __restrict__ out, int n2){
  int i = blockIdx.x*256 + threadIdx.x;
  if (i < n2){
    uint32_t a = bf16_of(in[2*i]);
    uint32_t b = bf16_of(in[2*i + 1]);
    out[i] = a | (b << 16);
  }
}

// ---------- bf16 GEMM: C[M][N] = A[M][K](bf16 pairs) @ (Whi+Wlo)[N][K]^T + bias ----------
// 128x128x32 tiles, 256 thr (2x2 waves), 2 MFMA products per fragment pair.
__global__ __launch_bounds__(256) void gemm_bf16(
    const uint32_t* __restrict__ A, const uint16_t* __restrict__ Whi,
    const uint16_t* __restrict__ Wlo, const float* __restrict__ bias,
    float* __restrict__ C, int N, int K)
{
  __shared__ uint32_t Al[128*16];   // 8 KB: A tile 128 rows x 32 K bf16
  __shared__ uint16_t Wh[128*32];   // 8 KB
  __shared__ uint16_t Wl[128*32];   // 8 KB
  const int tid  = threadIdx.x;
  const int lane = tid & 63;
  const int w    = tid >> 6;
  const int wm   = w >> 1, wn = w & 1;
  const int lr   = lane & 15, kg = lane >> 4;
  const int bm   = blockIdx.x, bn = blockIdx.y;
  const int K2   = K >> 1;

  const uint32_t* Ag  = A   + (size_t)bm*128*K2;
  const uint16_t* Whg = Whi + (size_t)bn*128*K;
  const uint16_t* Wlg = Wlo + (size_t)bn*128*K;

  f32x4 acc[4][4];
#pragma unroll
  for (int i = 0; i < 4; ++i)
#pragma unroll
    for (int j = 0; j < 4; ++j) acc[i][j] = (f32x4){0.f,0.f,0.f,0.f};

  for (int ks = 0; ks < K; ks += 32){
    __syncthreads();
    // stage A tile: 512 x 16B chunks; slot s: row=s>>2, pos=s&3, swizzled src
#pragma unroll
    for (int j = 0; j < 2; ++j){
      int s = j*256 + tid;
      int row = s >> 2, pos = s & 3;
      int ps = pos ^ (row & 3);
      gl16(Ag + (size_t)row*K2 + (ks >> 1) + ps*4, (char*)Al + j*4096 + tid*16);
    }
    // stage W tiles (hi/lo), 16B chunks of 8 bf16
#pragma unroll
    for (int j = 0; j < 2; ++j){
      int c = j*256 + tid;
      int row = c >> 2, kc = c & 3;
      int kcs = kc ^ (row & 3);
      gl16(Whg + (size_t)row*K + ks + kcs*8, (char*)Wh + c*16);
      gl16(Wlg + (size_t)row*K + ks + kcs*8, (char*)Wl + c*16);
    }
    __syncthreads();

    short8 ah[4];
#pragma unroll
    for (int mt = 0; mt < 4; ++mt){
      int row = wm*64 + mt*16 + lr;
      int ps  = kg ^ (row & 3);
      ah[mt] = *(const short8*)&Al[row*16 + ps*4];
    }
#pragma unroll
    for (int nt = 0; nt < 4; ++nt){
      int row = wn*64 + nt*16 + lr;
      int kc  = kg ^ (row & 3);
      short8 whf = *(const short8*)&Wh[row*32 + kc*8];
      short8 wlf = *(const short8*)&Wl[row*32 + kc*8];
#pragma unroll
      for (int mt = 0; mt < 4; ++mt){
        acc[mt][nt] = __builtin_amdgcn_mfma_f32_16x16x32_bf16(ah[mt], whf, acc[mt][nt], 0,0,0);
        acc[mt][nt] = __builtin_amdgcn_mfma_f32_16x16x32_bf16(ah[mt], wlf, acc[mt][nt], 0,0,0);
      }
    }
  }
#pragma unroll
  for (int nt = 0; nt < 4; ++nt){
    int col = bn*128 + wn*64 + nt*16 + lr;
    float bv = bias[col];
#pragma unroll
    for (int mt = 0; mt < 4; ++mt){
#pragma unroll
      for (int r = 0; r < 4; ++r){
        int rowg = bm*128 + wm*64 + mt*16 + kg*4 + r;
        C[(size_t)rowg*N + col] = acc[mt][nt][r] + bv;
      }
    }
  }
}

// ---------- persistent wavefront scan: bf16 h, 4-slot dbuf, split epilogue ----------
// 192 WGs x 256 thr. group = wg/64: 0 = L0 rec (t=r), 1 = Wih1*h0 (t=r-1),
// 2 = L1 rec (t=r-2). sub=wg%64: rh=sub>>5 (rows 32*rh), ci=sub&31 (cols 32*ci).
// Wave w: mt=w&1 (16-row half), kh=w>>1 (K-half). h stored as bf16 pairs
// (HID/2 u32 per row). Per-wave A slice = 16 rows x 512 bf16 = 16 KB, staged
// in 8 chunks x 2 KB through a private 8 KB 4-slot buffer, 3-deep prefetch,
// counted vmcnt(6/4/2/0). 2 MFMA products (A*Whi + A*Wlo). kh-partners
// exchange partials via LDS; kh0 stores colA tile, kh1 colB. 2 barriers/round.
__global__ __launch_bounds__(256, 1) void rnn_persist(
    const float* __restrict__ pre0, uint32_t* __restrict__ h0seq,
    uint32_t* __restrict__ pre1, uint32_t* __restrict__ h1seq,
    const uint16_t* __restrict__ Whh0h, const uint16_t* __restrict__ Whh0l,
    const uint16_t* __restrict__ Wih1h, const uint16_t* __restrict__ Wih1l,
    const uint16_t* __restrict__ Whh1h, const uint16_t* __restrict__ Whh1l,
    const float* __restrict__ bhh0, const float* __restrict__ bih1,
    const float* __restrict__ bhh1,
    uint32_t* h0s, uint32_t* h1s,
    uint32_t* ctr, int T, int first)
{
  __shared__ short WhF[32768];          // 64 KB, fragment-linear
  __shared__ short WlF[32768];          // 64 KB
  __shared__ uint32_t Stage[4][2048];   // 4 waves x (4 slots x 2 KB) = 32 KB
  const int tid  = threadIdx.x;
  const int lane = tid & 63;
  const int w    = tid >> 6;                 // 0..3
  const int mt   = w & 1, kh = w >> 1;
  const int lr   = lane & 15, kg = lane >> 4;
  const int wg   = blockIdx.x;
  const int group = wg / G_WGS;              // 0,1,2
  const int sub  = wg % G_WGS;
  const int rh   = sub >> 5;                 // rows 32*rh
  const int ci   = sub & 31;                 // cols 32*ci
  const int col0 = ci * 32;
  const int H2   = HID/2;

  // per-producer flag blocks: (group*2+rh)*64 u32 (32 used)
  uint32_t* fmy = ctr + (group*2 + rh)*64;
  uint32_t* f0  = ctr + (0*2 + rh)*64;
  uint32_t* f1  = ctr + (1*2 + rh)*64;
  uint32_t* f2  = ctr + (2*2 + rh)*64;

  const uint16_t* Whg = (group == 0) ? Whh0h : (group == 1) ? Wih1h : Whh1h;
  const uint16_t* Wlg = (group == 0) ? Whh0l : (group == 1) ? Wih1l : Whh1l;

  // ---- stage W slice into LDS once, fragment-linear ----
#pragma unroll
  for (int it = 0; it < 16; ++it){
    int lin = it*256 + tid;          // 0..4095
    int c = lin >> 7, j = lin & 127;
    int dst = (((c >> 4)*32 + (j >> 2))*64 + (j & 3)*16 + (c & 15))*8;
    *(uint4*)&WhF[dst] = *(const uint4*)&Whg[(size_t)(col0 + c)*HID + j*8];
    *(uint4*)&WlF[dst] = *(const uint4*)&Wlg[(size_t)(col0 + c)*HID + j*8];
  }
  __syncthreads();

  // lane constants
  const int p3r = ((lr & 3) << 1) | ((lr >> 2) & 1);   // 3-bit swizzle of my A row
  const int fb0 = 0*16384 + lane*8;                    // W frag base ntw=0 (colA)
  const int fb1 = 1*16384 + lane*8;                    // W frag base ntw=1 (colB)
  const int colE = col0 + kh*16 + lr;                  // my epilogue column
  float bvE = 0.f;
  if (group == 0) bvE = bhh0[colE];
  else if (group == 1) bvE = bih1[colE] + bhh1[colE];

  const int R = T + 2;
  for (int r = 0; r < R; ++r){
    const int t = r - group;
    const bool valid = (t >= 0 && t < T);

    if (valid){
      // ---- round-start rendezvous: each wave polls its own dependencies ----
      if (group == 0){
        if (t > 0) waitflags32(f0, (uint32_t)t);
      } else if (group == 1){
        waitflags32(f0, (uint32_t)(t+1));
      } else {
        waitflags32(f1, (uint32_t)(t+1));
        if (t > 0) waitflags32(f2, (uint32_t)t);
      }
      asm volatile("" ::: "memory");

      const uint32_t* Ap;   // bf16-pair h buffer
      if (group == 0)
        Ap = (t == 0) ? (first ? (const uint32_t*)0 : h0s)
                      : h0seq + (size_t)(t-1)*(BAT*H2);
      else if (group == 1)
        Ap = h0seq + (size_t)t*(BAT*H2);
      else
        Ap = (t == 0) ? (first ? (const uint32_t*)0 : h1s)
                      : h1seq + (size_t)(t-1)*(BAT*H2);

      // ---- epilogue-input (pv) loads for my column tile (issued first) ----
      const int rowb = rh*32 + mt*16 + kg*4;
      const size_t idxP = (size_t)t*(BAT*HID) + (size_t)rowb*HID + colE;  // f32 bufs
      float pv[4] = {0,0,0,0};
      if (group == 0){
#pragma unroll
        for (int q = 0; q < 4; ++q) pv[q] = pre0[idxP + (size_t)q*HID];
      } else if (group == 2){
#pragma unroll
        for (int q = 0; q < 4; ++q) pv[q] = __uint_as_float(pre1[idxP + (size_t)q*HID]);
      }

      f32x4 acc[2][2];   // [ntw][chain]
#pragma unroll
      for (int i = 0; i < 2; ++i)
#pragma unroll
        for (int j = 0; j < 2; ++j) acc[i][j] = (f32x4){0.f,0.f,0.f,0.f};

      if (Ap){
        // chunk c (0..7): rows [base,+16) x K-bf16 [kh*512+c*64,+64) = 2 KB
        const uint32_t* Aw = Ap + (size_t)(rh*32 + mt*16)*H2 + kh*256;
        auto STAGE = [&](int c){
          char* db = (char*)&Stage[w][(c & 3)*512];
#pragma unroll
          for (int j = 0; j < 2; ++j){
            const int s   = j*64 + lane;
            const int row = s >> 3, pos = s & 7;
            const int p3  = ((row & 3) << 1) | ((row >> 2) & 1);
            gl16(Aw + (size_t)row*H2 + c*32 + (pos ^ p3)*4, db + j*1024 + lane*16);
          }
        };

        STAGE(0); STAGE(1); STAGE(2);
#pragma unroll
        for (int c = 0; c < 8; ++c){
          if (c < 5){
            STAGE(c+3);                                        // 3-deep, other slot
            asm volatile("s_waitcnt vmcnt(6)" ::: "memory");   // chunk c landed
          } else if (c == 5) asm volatile("s_waitcnt vmcnt(4)" ::: "memory");
          else if (c == 6)   asm volatile("s_waitcnt vmcnt(2)" ::: "memory");
          else               asm volatile("s_waitcnt vmcnt(0)" ::: "memory");
          const char* Ab = (const char*)&Stage[w][(c & 3)*512] + lr*128;
#pragma unroll
          for (int j = 0; j < 2; ++j){
            short8 af = *(const short8*)(Ab + ((((j << 2) | kg) ^ p3r)*16));
            const int ks = kh*16 + c*2 + j;
            short8 wh0 = *(const short8*)&WhF[fb0 + ks*512];
            short8 wl0 = *(const short8*)&WlF[fb0 + ks*512];
            short8 wh1 = *(const short8*)&WhF[fb1 + ks*512];
            short8 wl1 = *(const short8*)&WlF[fb1 + ks*512];
            acc[0][c & 1] = __builtin_amdgcn_mfma_f32_16x16x32_bf16(af, wh0, acc[0][c & 1], 0,0,0);
            acc[0][c & 1] = __builtin_amdgcn_mfma_f32_16x16x32_bf16(af, wl0, acc[0][c & 1], 0,0,0);
            acc[1][c & 1] = __builtin_amdgcn_mfma_f32_16x16x32_bf16(af, wh1, acc[1][c & 1], 0,0,0);
            acc[1][c & 1] = __builtin_amdgcn_mfma_f32_16x16x32_bf16(af, wl1, acc[1][c & 1], 0,0,0);
          }
        }
      }
      f32x4 sA = acc[0][0] + acc[0][1];   // my partial, colA tile
      f32x4 sB = acc[1][0] + acc[1][1];   // my partial, colB tile

      // ---- symmetric partial exchange: kh0 gives sB, kh1 gives sA ----
      {
        f32x4 give = (kh == 0) ? sB : sA;
        *(f32x4*)&Stage[w][lane*8] = give;
        asm volatile("s_waitcnt lgkmcnt(0)" ::: "memory");
      }
      __builtin_amdgcn_s_barrier();          // A: partials visible
      {
        const int pw = w ^ 2;
        f32x4 part = *(const f32x4*)&Stage[pw][lane*8];
        f32x4 sE = (kh == 0) ? (sA + part) : (part + sB);

        // ---- split epilogue: this wave finishes + stores its own col tile ----
        if (group == 1){
#pragma unroll
          for (int q = 0; q < 4; ++q)
            astore32(pre1 + idxP + (size_t)q*HID, __float_as_uint(sE[q] + bvE));
        } else {
          uint32_t* hseq = (group == 0) ? h0seq : h1seq;
          uint32_t* hst  = (group == 0) ? h0s   : h1s;
          const size_t idxH = (size_t)t*(BAT*H2) + (size_t)rowb*H2 + (colE >> 1);
#pragma unroll
          for (int q = 0; q < 4; ++q){
            float v = tanhf(sE[q] + pv[q] + ((group == 0) ? bvE : 0.f));
            uint32_t b = bf16_of(v);
            uint32_t o = (uint32_t)__shfl_xor((int)b, 1, 64);
            if (!(lr & 1)){
              uint32_t word = b | (o << 16);     // low = even col
              astore32(hseq + idxH + (size_t)q*H2, word);
              if (t == T-1) astore32(hst + (size_t)(rowb + q)*H2 + (colE >> 1), word);
            }
          }
        }
        asm volatile("s_waitcnt vmcnt(0)" ::: "memory");   // drain my stores
      }
      __builtin_amdgcn_s_barrier();          // B: all stores drained, slots reusable
      if (tid == 0)
        astore32(fmy + ci, (uint32_t)(t + 1));
    }
  }
}

// ---------- hidden output from carried states (bf16 pairs -> f32) ----------
__global__ void extract_hidden(const uint32_t* __restrict__ h0s,
                               const uint32_t* __restrict__ h1s,
                               float* __restrict__ out){
  int i = blockIdx.x*256 + threadIdx.x;   // 0..131071
  int j = i & 65535;                       // b*1024 + g
  const uint32_t* hs = (i >> 16) ? h1s : h0s;
  uint32_t wv = hs[j >> 1];
  uint32_t half = (j & 1) ? (wv >> 16) : (wv & 0xFFFFu);
  out[(size_t)SB*INF + i] = __uint_as_float(half << 16);
}

// ---------- host ----------
extern "C" void kernel_launch(void* const* d_in, const int* in_sizes, int n_in,
                              void* d_out, int out_size, void* d_ws, size_t ws_size,
                              hipStream_t stream)
{
  const float* x    = (const float*)d_in[0];
  const float* W_in = (const float*)d_in[1];
  const float* b_in = (const float*)d_in[2];
  const float* W_ih = (const float*)d_in[3];   // [2][H][H]
  const float* W_hh = (const float*)d_in[4];   // [2][H][H]
  const float* b_ih = (const float*)d_in[5];   // [2][H]
  const float* b_hh = (const float*)d_in[6];   // [2][H]
  const float* W_out= (const float*)d_in[7];   // [I][H]
  const float* b_out= (const float*)d_in[8];
  float* out = (float*)d_out;
  (void)in_sizes; (void)n_in; (void)out_size;

  // ---- choose chunk length T to fit ws_size ----
  // perT = pre0(256K) + h0(128K) + pre1(256K) + h1(128K) + xp(32K) = 819200 B
  const size_t fixedB = 16500000;
  const size_t perT   = 819200;
  int T = 512;
  while (T > 2 && fixedB + (size_t)T*perT > ws_size) T >>= 1;
  const int nchunk = SEQ / T;

  char* ws = (char*)d_ws;
  size_t off = 0;
  auto alloc = [&](size_t bytes)->void*{
    void* p = ws + off; off += (bytes + 255) & ~(size_t)255; return p;
  };
  float*    pre0s  = (float*)   alloc((size_t)T*BAT*HID*4);
  uint32_t* h0seq  = (uint32_t*)alloc((size_t)T*BAT*(HID/2)*4);
  uint32_t* pre1s  = (uint32_t*)alloc((size_t)T*BAT*HID*4);
  uint32_t* h1seq  = (uint32_t*)alloc((size_t)T*BAT*(HID/2)*4);
  uint32_t* xp     = (uint32_t*)alloc((size_t)T*BAT*(INF/2)*4);
  float*    WcombF = (float*)   alloc((size_t)HID*INF*4);
  uint16_t* Wc_hi  = (uint16_t*)alloc((size_t)HID*INF*2);
  uint16_t* Wc_lo  = (uint16_t*)alloc((size_t)HID*INF*2);
  uint16_t* Wih1_hi= (uint16_t*)alloc((size_t)HID*HID*2);
  uint16_t* Wih1_lo= (uint16_t*)alloc((size_t)HID*HID*2);
  uint16_t* Whh0_hi= (uint16_t*)alloc((size_t)HID*HID*2);
  uint16_t* Whh0_lo= (uint16_t*)alloc((size_t)HID*HID*2);
  uint16_t* Whh1_hi= (uint16_t*)alloc((size_t)HID*HID*2);
  uint16_t* Whh1_lo= (uint16_t*)alloc((size_t)HID*HID*2);
  uint16_t* Wout_hi= (uint16_t*)alloc((size_t)INF*HID*2);
  uint16_t* Wout_lo= (uint16_t*)alloc((size_t)INF*HID*2);
  float*    bcomb  = (float*)   alloc((size_t)HID*4);
  uint32_t* h0s    = (uint32_t*)alloc((size_t)BAT*(HID/2)*4);
  uint32_t* h1s    = (uint32_t*)alloc((size_t)BAT*(HID/2)*4);
  uint32_t* ctr    = (uint32_t*)alloc(8192);

  // ---- prep ----
  wcomb_kernel<<<HID/16, 256, 0, stream>>>(W_ih, W_in, WcombF);
  bcomb_kernel<<<HID, 256, 0, stream>>>(W_ih, b_in, b_ih, bcomb);
  split_w<<<(HID*INF+255)/256, 256, 0, stream>>>(WcombF, Wc_hi, Wc_lo, HID*INF);
  split_w<<<(HID*HID+255)/256, 256, 0, stream>>>(W_ih + (size_t)HID*HID, Wih1_hi, Wih1_lo, HID*HID);
  split_w<<<(HID*HID+255)/256, 256, 0, stream>>>(W_hh, Whh0_hi, Whh0_lo, HID*HID);
  split_w<<<(HID*HID+255)/256, 256, 0, stream>>>(W_hh + (size_t)HID*HID, Whh1_hi, Whh1_lo, HID*HID);
  split_w<<<(INF*HID+255)/256, 256, 0, stream>>>(W_out, Wout_hi, Wout_lo, INF*HID);

  // ---- chunked pipeline ----
  for (int c = 0; c < nchunk; ++c){
    const float* xc = x + (size_t)c*T*BAT*INF;
    pack_xb<<<T*BAT*(INF/2)/256, 256, 0, stream>>>(xc, xp, T*BAT*(INF/2));
    // pre0 chunk = x(bf16) @ Wcomb^T + bcomb
    gemm_bf16<<<dim3(T*64/128, HID/128), 256, 0, stream>>>(xp, Wc_hi, Wc_lo, bcomb, pre0s, HID, INF);
    // wavefront scan over the chunk (both layers + pre1 fused)
    hipMemsetAsync(ctr, 0, 8192, stream);
    rnn_persist<<<NWG, 256, 0, stream>>>(
        pre0s, h0seq, pre1s, h1seq,
        Whh0_hi, Whh0_lo, Wih1_hi, Wih1_lo, Whh1_hi, Whh1_lo,
        b_hh, b_ih + HID, b_hh + HID, h0s, h1s, ctr, T, (c == 0) ? 1 : 0);
    // out chunk = h1(bf16) @ Wout^T + b_out
    gemm_bf16<<<dim3(T*64/128, INF/128), 256, 0, stream>>>(h1seq, Wout_hi, Wout_lo,
                                                           b_out, out + (size_t)c*T*BAT*INF, INF, HID);
  }
  extract_hidden<<<(2*BAT*HID)/256, 256, 0, stream>>>(h0s, h1s, out);
}